// Round 2
// baseline (1903.131 us; speedup 1.0000x reference)
//
#include <hip/hip_runtime.h>
#include <cstdint>
#include <cstddef>

// Problem constants (fixed by the reference setup_inputs).
#define NN 100000
#define EE 500000
#define DD 128
#define GG 512
#define LL 4
#define BN_EPS 1e-5f

// ---------------- CSR build ----------------
// NOTE: harness passes integer inputs as int32 (jnp.int64 is downcast).

__global__ void k_hist(const int* __restrict__ ei, int* __restrict__ cnt) {
  int e = blockIdx.x * 256 + threadIdx.x;
  if (e < EE) {
    int d = ei[EE + e];
    if (d >= 0 && d < NN) atomicAdd(&cnt[d], 1);
  }
}

__global__ void k_scan(const int* __restrict__ cnt, int* __restrict__ rs,
                       int* __restrict__ cur, int n) {
  __shared__ int sm[1024];
  int t = threadIdx.x;
  int chunk = (n + 1023) / 1024;
  int lo = t * chunk, hi = lo + chunk;
  if (hi > n) hi = n;
  int s = 0;
  for (int i = lo; i < hi; ++i) s += cnt[i];
  sm[t] = s;
  __syncthreads();
  // inclusive Hillis-Steele
  for (int off = 1; off < 1024; off <<= 1) {
    int v = (t >= off) ? sm[t - off] : 0;
    __syncthreads();
    sm[t] += v;
    __syncthreads();
  }
  int run = (t == 0) ? 0 : sm[t - 1];
  for (int i = lo; i < hi; ++i) {
    rs[i] = run;
    cur[i] = run;
    run += cnt[i];
  }
  if (t == 1023) rs[n] = run;
}

__global__ void k_fill(const int* __restrict__ ei, int* __restrict__ cur,
                       int* __restrict__ ci) {
  int e = blockIdx.x * 256 + threadIdx.x;
  if (e < EE) {
    int s = ei[e];
    int d = ei[EE + e];
    if (d >= 0 && d < NN && s >= 0 && s < NN) {
      int pos = atomicAdd(&cur[d], 1);
      if (pos >= 0 && pos < EE) ci[pos] = s;  // order irrelevant (sum)
    }
  }
}

// ---------------- aggregation: h0 = (1+eps)*xn + sum_{nbrs} xn ----------------
// xn = mode ? relu(tsc*x + tsh) : x   (BN+ReLU of previous layer applied on read)

__global__ __launch_bounds__(256) void k_agg(
    const float* __restrict__ X, const int* __restrict__ rs,
    const int* __restrict__ ci, const float* __restrict__ epsv, int l, int mode,
    const float* __restrict__ tsc, const float* __restrict__ tsh,
    float* __restrict__ h0, int n) {
  int idx = blockIdx.x * 256 + threadIdx.x;
  int node = idx >> 7;
  int c = idx & 127;
  if (node >= n) return;
  float a = 1.f, b = 0.f;
  if (mode) { a = tsc[c]; b = tsh[c]; }
  float v = X[(size_t)node * DD + c];
  if (mode) v = fmaxf(0.f, v * a + b);
  float acc = (1.f + epsv[l]) * v;
  int e0 = rs[node], e1 = rs[node + 1];
  for (int j = e0; j < e1; ++j) {
    int nb = ci[j];
    float u = X[(size_t)nb * DD + c];
    if (mode) u = fmaxf(0.f, u * a + b);
    acc += u;
  }
  h0[(size_t)node * DD + c] = acc;
}

// ---------------- fused GEMM: C = xform(A) @ B + bias, plus column stats ----------------
// xform per element of A (K-dim index k): mode ? relu(tsc[k]*a + tsh[k]) : a
// Block tile 64x128, BK=64, 256 threads, 4x8 micro-tile.

#define BM 64
#define BN_T 128
#define BK 64
#define BKP 68  // 68*4B = 272B row stride: 16B aligned, conflict-benign

__global__ __launch_bounds__(256) void k_gemm(
    const float* __restrict__ A, int K, int mode, const float* __restrict__ tsc,
    const float* __restrict__ tsh, const float* __restrict__ B, int NC,
    const float* __restrict__ bias, float* __restrict__ C,
    float* __restrict__ colsum, float* __restrict__ colsq, int n) {
  __shared__ float As[BM][BKP];
  __shared__ float Bs[BK][BN_T];
  int tid = threadIdx.x;
  int tx = tid & 15, ty = tid >> 4;
  int row0 = blockIdx.x * BM, col0 = blockIdx.y * BN_T;

  float acc[4][8];
#pragma unroll
  for (int i = 0; i < 4; ++i)
#pragma unroll
    for (int j = 0; j < 8; ++j) acc[i][j] = 0.f;

  for (int k0 = 0; k0 < K; k0 += BK) {
    // A tile: 64 rows x 64 k  (1024 float4, 4 per thread)
#pragma unroll
    for (int it = 0; it < 4; ++it) {
      int f = tid + it * 256;
      int r = f >> 4;
      int kq = (f & 15) << 2;
      int gr = row0 + r;
      float4 v = make_float4(0.f, 0.f, 0.f, 0.f);
      if (gr < n) v = *(const float4*)(A + (size_t)gr * K + k0 + kq);
      if (mode) {
        int kk = k0 + kq;
        v.x = fmaxf(0.f, v.x * tsc[kk + 0] + tsh[kk + 0]);
        v.y = fmaxf(0.f, v.y * tsc[kk + 1] + tsh[kk + 1]);
        v.z = fmaxf(0.f, v.z * tsc[kk + 2] + tsh[kk + 2]);
        v.w = fmaxf(0.f, v.w * tsc[kk + 3] + tsh[kk + 3]);
      }
      *(float4*)(&As[r][kq]) = v;
    }
    // B tile: 64 k x 128 cols (2048 float4, 8 per thread)
#pragma unroll
    for (int it = 0; it < 8; ++it) {
      int f = tid + it * 256;
      int r = f >> 5;
      int cq = (f & 31) << 2;
      *(float4*)(&Bs[r][cq]) = *(const float4*)(B + (size_t)(k0 + r) * NC + col0 + cq);
    }
    __syncthreads();
#pragma unroll 8
    for (int k = 0; k < BK; ++k) {
      float a0 = As[ty * 4 + 0][k];
      float a1 = As[ty * 4 + 1][k];
      float a2 = As[ty * 4 + 2][k];
      float a3 = As[ty * 4 + 3][k];
      float4 b0 = *(float4*)(&Bs[k][tx * 8]);
      float4 b1 = *(float4*)(&Bs[k][tx * 8 + 4]);
      float bv[8] = {b0.x, b0.y, b0.z, b0.w, b1.x, b1.y, b1.z, b1.w};
      float av[4] = {a0, a1, a2, a3};
#pragma unroll
      for (int i = 0; i < 4; ++i)
#pragma unroll
        for (int j = 0; j < 8; ++j) acc[i][j] = fmaf(av[i], bv[j], acc[i][j]);
    }
    __syncthreads();
  }

  // epilogue: bias add, C write, per-column (sum, sumsq) over valid rows
  int cbase = col0 + tx * 8;
  float bia[8];
#pragma unroll
  for (int j = 0; j < 8; ++j) bia[j] = bias[cbase + j];
  float s8[8], q8[8];
#pragma unroll
  for (int j = 0; j < 8; ++j) { s8[j] = 0.f; q8[j] = 0.f; }
#pragma unroll
  for (int i = 0; i < 4; ++i) {
    int gr = row0 + ty * 4 + i;
    if (gr < n) {
      float e[8];
#pragma unroll
      for (int j = 0; j < 8; ++j) {
        e[j] = acc[i][j] + bia[j];
        s8[j] += e[j];
        q8[j] += e[j] * e[j];
      }
      float* cp = C + (size_t)gr * NC + cbase;
      *(float4*)(cp) = make_float4(e[0], e[1], e[2], e[3]);
      *(float4*)(cp + 4) = make_float4(e[4], e[5], e[6], e[7]);
    }
  }
  // block reduce columns over ty (16), reusing As as scratch (needs 4096 floats <= 4352)
  float* red = &As[0][0];
  __syncthreads();
#pragma unroll
  for (int j = 0; j < 8; ++j) {
    red[ty * 128 + tx * 8 + j] = s8[j];
    red[2048 + ty * 128 + tx * 8 + j] = q8[j];
  }
  __syncthreads();
  if (tid < BN_T) {
    float ss = 0.f, qq = 0.f;
#pragma unroll
    for (int t = 0; t < 16; ++t) {
      ss += red[t * 128 + tid];
      qq += red[2048 + t * 128 + tid];
    }
    atomicAdd(&colsum[col0 + tid], ss);
    atomicAdd(&colsq[col0 + tid], qq);
  }
}

// ---------------- BN stat finalize: per-column scale/shift ----------------

__global__ void k_fin(const float* __restrict__ colsum, const float* __restrict__ colsq,
                      const float* __restrict__ g, const float* __restrict__ be,
                      float* __restrict__ osc, float* __restrict__ osh, int nc,
                      float invn) {
  int c = threadIdx.x;
  if (c < nc) {
    float m = colsum[c] * invn;
    float v = fmaxf(colsq[c] * invn - m * m, 0.f);
    float sc = g[c] * rsqrtf(v + BN_EPS);
    osc[c] = sc;
    osh[c] = be[c] - m * sc;
  }
}

// ---------------- pooling (batch sorted -> contiguous ranges) ----------------

static __device__ __forceinline__ int lb_i32(const int* a, int n, int key) {
  int lo = 0, hi = n;
  while (lo < hi) {
    int mid = (lo + hi) >> 1;
    if (a[mid] < key) lo = mid + 1; else hi = mid;
  }
  return lo;
}

__global__ void k_pool(const float* __restrict__ X, const int* __restrict__ batch,
                       const float* __restrict__ tsc, const float* __restrict__ tsh,
                       float* __restrict__ z, int n) {
  int g = blockIdx.x;
  int c = threadIdx.x;  // 128
  __shared__ int slo, shi;
  if (c == 0) {
    slo = lb_i32(batch, n, g);
    shi = lb_i32(batch, n, g + 1);
  }
  __syncthreads();
  int lo = slo, hi = shi;
  float a = tsc[c], b = tsh[c];
  float s = 0.f, m = -3.402823466e38f;
  for (int i = lo; i < hi; ++i) {
    float v = fmaxf(0.f, X[(size_t)i * DD + c] * a + b);
    s += v;
    m = fmaxf(m, v);
  }
  float cntf = (float)(hi - lo);
  z[(size_t)g * 384 + c] = s;
  z[(size_t)g * 384 + 128 + c] = s / fmaxf(cntf, 1.f);
  z[(size_t)g * 384 + 256 + c] = m;
}

// ---------------- classifier head ----------------

__global__ void k_cls1(const float* __restrict__ z, const float* __restrict__ cW1,
                       const float* __restrict__ cb1, float* __restrict__ z1,
                       float* __restrict__ colsum, float* __restrict__ colsq) {
  __shared__ float zr[384];
  int g = blockIdx.x;
  int c = threadIdx.x;  // 128
  for (int i = c; i < 384; i += 128) zr[i] = z[(size_t)g * 384 + i];
  __syncthreads();
  float s = cb1[c];
#pragma unroll 4
  for (int k = 0; k < 384; ++k) s = fmaf(zr[k], cW1[(size_t)k * 128 + c], s);
  z1[(size_t)g * 128 + c] = s;
  atomicAdd(&colsum[c], s);
  atomicAdd(&colsq[c], s * s);
}

__global__ void k_cls2(const float* __restrict__ z1, const float* __restrict__ csc,
                       const float* __restrict__ csh, const float* __restrict__ cW2,
                       const float* __restrict__ cb2, const float* __restrict__ cW3,
                       const float* __restrict__ cb3, float* __restrict__ out) {
  __shared__ float z1n[128];
  __shared__ float z2s[64];
  int g = blockIdx.x;
  int t = threadIdx.x;  // 128
  z1n[t] = fmaxf(0.f, z1[(size_t)g * 128 + t] * csc[t] + csh[t]);
  __syncthreads();
  if (t < 64) {
    float s = cb2[t];
#pragma unroll 4
    for (int k = 0; k < 128; ++k) s = fmaf(z1n[k], cW2[(size_t)k * 64 + t], s);
    z2s[t] = fmaxf(0.f, s);
  }
  __syncthreads();
  if (t < 2) {
    float s = cb3[t];
#pragma unroll 4
    for (int c = 0; c < 64; ++c) s = fmaf(z2s[c], cW3[(size_t)c * 2 + t], s);
    out[(size_t)g * 2 + t] = s;
  }
}

// ---------------- launch ----------------

extern "C" void kernel_launch(void* const* d_in, const int* in_sizes, int n_in,
                              void* d_out, int out_size, void* d_ws, size_t ws_size,
                              hipStream_t stream) {
  const float* x = (const float*)d_in[0];
  const int* ei = (const int*)d_in[1];     // int32 (harness downcasts int64)
  const int* batch = (const int*)d_in[2];  // int32
  const float* W1 = (const float*)d_in[4];
  const float* b1 = (const float*)d_in[5];
  const float* g1 = (const float*)d_in[6];
  const float* be1 = (const float*)d_in[7];
  const float* W2 = (const float*)d_in[8];
  const float* b2 = (const float*)d_in[9];
  const float* gbn = (const float*)d_in[10];
  const float* bbn = (const float*)d_in[11];
  const float* epsv = (const float*)d_in[12];
  const float* cW1 = (const float*)d_in[13];
  const float* cb1 = (const float*)d_in[14];
  const float* cg = (const float*)d_in[15];
  const float* cbeta = (const float*)d_in[16];
  const float* cW2 = (const float*)d_in[17];
  const float* cb2 = (const float*)d_in[18];
  const float* cW3 = (const float*)d_in[19];
  const float* cb3 = (const float*)d_in[20];
  float* out = (float*)d_out;

  char* p = (char*)d_ws;
  auto alloc = [&](size_t bytes) {
    char* r = p;
    p += (bytes + 255) & ~(size_t)255;
    return r;
  };
  int* cnt = (int*)alloc((size_t)NN * 4);
  int* rs = (int*)alloc((size_t)(NN + 1) * 4);
  int* cur = (int*)alloc((size_t)NN * 4);
  int* ci = (int*)alloc((size_t)EE * 4);
  float* h0 = (float*)alloc((size_t)NN * DD * 4);
  float* h1 = (float*)alloc((size_t)NN * 2 * DD * 4);
  float* xp = (float*)alloc((size_t)NN * DD * 4);
  float* stats = (float*)alloc(512 * 4);  // colsum[256] + colsq[256]
  float* colsum = stats;
  float* colsq = stats + 256;
  float* tsc1 = (float*)alloc(256 * 4);
  float* tsh1 = (float*)alloc(256 * 4);
  float* tscX = (float*)alloc(128 * 4);
  float* tshX = (float*)alloc(128 * 4);
  float* zbuf = (float*)alloc((size_t)GG * 384 * 4);
  float* z1 = (float*)alloc((size_t)GG * 128 * 4);
  (void)ws_size; (void)n_in; (void)in_sizes; (void)out_size;

  // CSR build (edges static across layers)
  hipMemsetAsync(cnt, 0, (size_t)NN * 4, stream);
  k_hist<<<(EE + 255) / 256, 256, 0, stream>>>(ei, cnt);
  k_scan<<<1, 1024, 0, stream>>>(cnt, rs, cur, NN);
  k_fill<<<(EE + 255) / 256, 256, 0, stream>>>(ei, cur, ci);

  const int gx = (NN + BM - 1) / BM;  // 1563
  const float* Xin = x;
  for (int l = 0; l < LL; ++l) {
    int mode = (l > 0) ? 1 : 0;
    k_agg<<<(NN * DD + 255) / 256, 256, 0, stream>>>(Xin, rs, ci, epsv, l, mode,
                                                     tscX, tshX, h0, NN);
    hipMemsetAsync(stats, 0, 512 * 4, stream);
    k_gemm<<<dim3(gx, 2), 256, 0, stream>>>(h0, 128, 0, nullptr, nullptr,
                                            W1 + (size_t)l * 128 * 256, 256,
                                            b1 + (size_t)l * 256, h1, colsum, colsq, NN);
    k_fin<<<1, 256, 0, stream>>>(colsum, colsq, g1 + (size_t)l * 256,
                                 be1 + (size_t)l * 256, tsc1, tsh1, 256, 1.0f / NN);
    hipMemsetAsync(stats, 0, 512 * 4, stream);
    k_gemm<<<dim3(gx, 1), 256, 0, stream>>>(h1, 256, 1, tsc1, tsh1,
                                            W2 + (size_t)l * 256 * 128, 128,
                                            b2 + (size_t)l * 128, xp, colsum, colsq, NN);
    k_fin<<<1, 256, 0, stream>>>(colsum, colsq, gbn + (size_t)l * 128,
                                 bbn + (size_t)l * 128, tscX, tshX, 128, 1.0f / NN);
    Xin = xp;
  }

  k_pool<<<GG, 128, 0, stream>>>(xp, batch, tscX, tshX, zbuf, NN);
  hipMemsetAsync(stats, 0, 512 * 4, stream);
  k_cls1<<<GG, 128, 0, stream>>>(zbuf, cW1, cb1, z1, colsum, colsq);
  k_fin<<<1, 256, 0, stream>>>(colsum, colsq, cg, cbeta, tscX, tshX, 128, 1.0f / GG);
  k_cls2<<<GG, 128, 0, stream>>>(z1, tscX, tshX, cW2, cb2, cW3, cb3, out);
}

// Round 4
// 1485.521 us; speedup vs baseline: 1.2811x; 1.2811x over previous
//
#include <hip/hip_runtime.h>
#include <cstdint>
#include <cstddef>

// Problem constants (fixed by the reference setup_inputs).
#define NN 100000
#define EE 500000
#define DD 128
#define GG 512
#define LL 4
#define BN_EPS 1e-5f

typedef __attribute__((ext_vector_type(8))) short short8;
typedef __attribute__((ext_vector_type(4))) float f32x4;

static __device__ __forceinline__ unsigned short f2bf(float f) {
  union { float f; unsigned u; } v;
  v.f = f;
  unsigned r = v.u + 0x7fffu + ((v.u >> 16) & 1u);  // RNE
  return (unsigned short)(r >> 16);
}

// ---------------- CSR build (int32 inputs) ----------------

__global__ void k_hist(const int* __restrict__ ei, int* __restrict__ cnt) {
  int e = blockIdx.x * 256 + threadIdx.x;
  if (e < EE) {
    int d = ei[EE + e];
    if (d >= 0 && d < NN) atomicAdd(&cnt[d], 1);
  }
}

// phase A: per-block (1024 elems) partial sums
__global__ void k_part(const int* __restrict__ cnt, int* __restrict__ part) {
  __shared__ int sm[1024];
  int t = threadIdx.x;
  int i = blockIdx.x * 1024 + t;
  sm[t] = (i < NN) ? cnt[i] : 0;
  __syncthreads();
  for (int off = 512; off > 0; off >>= 1) {
    if (t < off) sm[t] += sm[t + off];
    __syncthreads();
  }
  if (t == 0) part[blockIdx.x] = sm[0];
}

// phase B: exclusive scan of the (<=128) partials
__global__ void k_scanpart(const int* __restrict__ part, int* __restrict__ partx, int nb) {
  __shared__ int sm[128];
  int t = threadIdx.x;
  int v = (t < nb) ? part[t] : 0;
  sm[t] = v;
  __syncthreads();
  for (int off = 1; off < 128; off <<= 1) {
    int u = (t >= off) ? sm[t - off] : 0;
    __syncthreads();
    sm[t] += u;
    __syncthreads();
  }
  if (t < nb) partx[t] = sm[t] - v;
}

// phase C: per-block inclusive scan + block offset -> rs/cur
__global__ void k_rs(const int* __restrict__ cnt, const int* __restrict__ partx,
                     int* __restrict__ rs, int* __restrict__ cur) {
  __shared__ int sm[1024];
  int t = threadIdx.x;
  int i = blockIdx.x * 1024 + t;
  int v = (i < NN) ? cnt[i] : 0;
  sm[t] = v;
  __syncthreads();
  for (int off = 1; off < 1024; off <<= 1) {
    int u = (t >= off) ? sm[t - off] : 0;
    __syncthreads();
    sm[t] += u;
    __syncthreads();
  }
  if (i < NN) {
    int excl = partx[blockIdx.x] + sm[t] - v;
    rs[i] = excl;
    cur[i] = excl;
    if (i == NN - 1) rs[NN] = excl + v;
  }
}

__global__ void k_fill(const int* __restrict__ ei, int* __restrict__ cur,
                       int* __restrict__ ci) {
  int e = blockIdx.x * 256 + threadIdx.x;
  if (e < EE) {
    int s = ei[e];
    int d = ei[EE + e];
    if (d >= 0 && d < NN && s >= 0 && s < NN) {
      int pos = atomicAdd(&cur[d], 1);
      if (pos >= 0 && pos < EE) ci[pos] = s;  // order irrelevant (sum)
    }
  }
}

// ---------------- weight convert: W -> W^T in bf16, once per call ----------------
// W1[l][k][nc] (K=128,NC=256) -> W1t[l][nc][k]; W2[l][k][nc] (K=256,NC=128) -> W2t[l][nc][k]

__global__ void k_conv(const float* __restrict__ W1, const float* __restrict__ W2,
                       unsigned short* __restrict__ W1t, unsigned short* __restrict__ W2t) {
  int idx = blockIdx.x * 256 + threadIdx.x;
  if (idx < 4 * 256 * 128) {
    {  // W1
      int l = idx >> 15, rem = idx & 32767;
      int nc = rem >> 7, k = rem & 127;
      W1t[idx] = f2bf(W1[(l << 15) + k * 256 + nc]);
    }
    {  // W2
      int l = idx >> 15, rem = idx & 32767;
      int nc = rem >> 8, k = rem & 255;
      W2t[idx] = f2bf(W2[(l << 15) + k * 128 + nc]);
    }
  }
}

// ---------------- aggregation: h0 = (1+eps)*xn + sum_{nbrs} xn ----------------
// xn = mode ? relu(tsc*x + tsh) : x   (BN+ReLU of previous layer applied on read)

__global__ __launch_bounds__(256) void k_agg(
    const float* __restrict__ X, const int* __restrict__ rs,
    const int* __restrict__ ci, const float* __restrict__ epsv, int l, int mode,
    const float* __restrict__ tsc, const float* __restrict__ tsh,
    float* __restrict__ h0, int n) {
  int idx = blockIdx.x * 256 + threadIdx.x;
  int node = idx >> 7;
  int c = idx & 127;
  if (node >= n) return;
  float a = 1.f, b = 0.f;
  if (mode) { a = tsc[c]; b = tsh[c]; }
  float v = X[(size_t)node * DD + c];
  if (mode) v = fmaxf(0.f, v * a + b);
  float acc = (1.f + epsv[l]) * v;
  int e0 = rs[node], e1 = rs[node + 1];
  for (int j = e0; j < e1; ++j) {
    int nb = ci[j];
    float u = X[(size_t)nb * DD + c];
    if (mode) u = fmaxf(0.f, u * a + b);
    acc += u;
  }
  h0[(size_t)node * DD + c] = acc;
}

// ---------------- MFMA bf16 GEMM: C = xform(A) @ B + bias, plus column stats -------
// xform per element of A (K index k): mode ? relu(tsc[k]*a + tsh[k]) : a, in fp32,
// then cast bf16. B passed pre-transposed bf16: Bt[nc][k]. Block tile 128x64, BK=64,
// 256 threads = 4 waves; wave handles 32 rows x 64 cols = 2x4 mfma frags (16x16x32).

#define GM 128
#define GN 64
#define GK 64
#define AST 72  // LDS row stride in ushorts (144B: 16B-aligned, conflict-benign)

__global__ __launch_bounds__(256) void k_gemm_mfma(
    const float* __restrict__ A, int K, int mode, const float* __restrict__ tsc,
    const float* __restrict__ tsh, const unsigned short* __restrict__ Bt, int NC,
    const float* __restrict__ bias, float* __restrict__ C,
    float* __restrict__ colsum, float* __restrict__ colsq, int n) {
  __shared__ unsigned short As[GM][AST];
  __shared__ unsigned short Bs[GN][AST];
  __shared__ float bsum[GN], bsq[GN];
  int tid = threadIdx.x;
  int lane = tid & 63, wave = tid >> 6;
  int quad = lane >> 4, l15 = lane & 15;
  int row0 = blockIdx.x * GM, col0 = blockIdx.y * GN;
  if (tid < GN) { bsum[tid] = 0.f; bsq[tid] = 0.f; }

  f32x4 acc[2][4];
#pragma unroll
  for (int i = 0; i < 2; ++i)
#pragma unroll
    for (int j = 0; j < 4; ++j) acc[i][j] = (f32x4){0.f, 0.f, 0.f, 0.f};

  for (int k0 = 0; k0 < K; k0 += GK) {
    // stage A: 128 rows x 64 k, fp32 -> (transform) -> bf16. 2048 float4 / 256 thr.
#pragma unroll
    for (int it = 0; it < 8; ++it) {
      int idx = tid + it * 256;
      int r = idx >> 4;
      int c4 = (idx & 15) << 2;  // k offset within tile
      int gr = row0 + r;
      float4 v = make_float4(0.f, 0.f, 0.f, 0.f);
      if (gr < n) v = *(const float4*)(A + (size_t)gr * K + k0 + c4);
      if (mode) {
        int kk = k0 + c4;
        v.x = fmaxf(0.f, v.x * tsc[kk + 0] + tsh[kk + 0]);
        v.y = fmaxf(0.f, v.y * tsc[kk + 1] + tsh[kk + 1]);
        v.z = fmaxf(0.f, v.z * tsc[kk + 2] + tsh[kk + 2]);
        v.w = fmaxf(0.f, v.w * tsc[kk + 3] + tsh[kk + 3]);
      }
      ushort4 o;
      o.x = f2bf(v.x); o.y = f2bf(v.y); o.z = f2bf(v.z); o.w = f2bf(v.w);
      *(ushort4*)(&As[r][c4]) = o;
    }
    // stage B: 64 cols x 64 k from Bt (already bf16, contiguous in k). 512 x 16B.
#pragma unroll
    for (int it = 0; it < 2; ++it) {
      int idx = tid + it * 256;
      int r = idx >> 3;
      int c8 = (idx & 7) << 3;
      uint4 v = *(const uint4*)(Bt + (size_t)(col0 + r) * K + k0 + c8);
      *(uint4*)(&Bs[r][c8]) = v;
    }
    __syncthreads();
#pragma unroll
    for (int kk = 0; kk < GK; kk += 32) {
      int ko = kk + quad * 8;
      short8 a0 = *(const short8*)(&As[wave * 32 + l15][ko]);
      short8 a1 = *(const short8*)(&As[wave * 32 + 16 + l15][ko]);
      short8 b0 = *(const short8*)(&Bs[l15][ko]);
      short8 b1 = *(const short8*)(&Bs[16 + l15][ko]);
      short8 b2 = *(const short8*)(&Bs[32 + l15][ko]);
      short8 b3 = *(const short8*)(&Bs[48 + l15][ko]);
      acc[0][0] = __builtin_amdgcn_mfma_f32_16x16x32_bf16(a0, b0, acc[0][0], 0, 0, 0);
      acc[0][1] = __builtin_amdgcn_mfma_f32_16x16x32_bf16(a0, b1, acc[0][1], 0, 0, 0);
      acc[0][2] = __builtin_amdgcn_mfma_f32_16x16x32_bf16(a0, b2, acc[0][2], 0, 0, 0);
      acc[0][3] = __builtin_amdgcn_mfma_f32_16x16x32_bf16(a0, b3, acc[0][3], 0, 0, 0);
      acc[1][0] = __builtin_amdgcn_mfma_f32_16x16x32_bf16(a1, b0, acc[1][0], 0, 0, 0);
      acc[1][1] = __builtin_amdgcn_mfma_f32_16x16x32_bf16(a1, b1, acc[1][1], 0, 0, 0);
      acc[1][2] = __builtin_amdgcn_mfma_f32_16x16x32_bf16(a1, b2, acc[1][2], 0, 0, 0);
      acc[1][3] = __builtin_amdgcn_mfma_f32_16x16x32_bf16(a1, b3, acc[1][3], 0, 0, 0);
    }
    __syncthreads();
  }

  // epilogue: bias add, C store, per-column (sum, sumsq) over valid rows.
  // C/D layout: col = l15, row = quad*4 + reg  [m89/m91 verified].
  float s4[4] = {0.f, 0.f, 0.f, 0.f}, q4[4] = {0.f, 0.f, 0.f, 0.f};
#pragma unroll
  for (int cf = 0; cf < 4; ++cf) {
    int col = col0 + cf * 16 + l15;
    float bv = bias[col];
#pragma unroll
    for (int rf = 0; rf < 2; ++rf) {
      int rbase = row0 + wave * 32 + rf * 16 + quad * 4;
#pragma unroll
      for (int reg = 0; reg < 4; ++reg) {
        int gr = rbase + reg;
        if (gr < n) {
          float e = acc[rf][cf][reg] + bv;
          C[(size_t)gr * NC + col] = e;
          s4[cf] += e;
          q4[cf] += e * e;
        }
      }
    }
  }
  // reduce across quads (lanes c, c+16, c+32, c+48 share the same column)
#pragma unroll
  for (int cf = 0; cf < 4; ++cf) {
    s4[cf] += __shfl_xor(s4[cf], 16, 64);
    s4[cf] += __shfl_xor(s4[cf], 32, 64);
    q4[cf] += __shfl_xor(q4[cf], 16, 64);
    q4[cf] += __shfl_xor(q4[cf], 32, 64);
  }
  if (quad == 0) {
#pragma unroll
    for (int cf = 0; cf < 4; ++cf) {
      atomicAdd(&bsum[cf * 16 + l15], s4[cf]);
      atomicAdd(&bsq[cf * 16 + l15], q4[cf]);
    }
  }
  __syncthreads();
  if (tid < GN) {
    atomicAdd(&colsum[col0 + tid], bsum[tid]);
    atomicAdd(&colsq[col0 + tid], bsq[tid]);
  }
}

// ---------------- BN stat finalize: per-column scale/shift ----------------

__global__ void k_fin(const float* __restrict__ colsum, const float* __restrict__ colsq,
                      const float* __restrict__ g, const float* __restrict__ be,
                      float* __restrict__ osc, float* __restrict__ osh, int nc,
                      float invn) {
  int c = threadIdx.x;
  if (c < nc) {
    float m = colsum[c] * invn;
    float v = fmaxf(colsq[c] * invn - m * m, 0.f);
    float sc = g[c] * rsqrtf(v + BN_EPS);
    osc[c] = sc;
    osh[c] = be[c] - m * sc;
  }
}

// ---------------- pooling (batch sorted -> contiguous ranges) ----------------

static __device__ __forceinline__ int lb_i32(const int* a, int n, int key) {
  int lo = 0, hi = n;
  while (lo < hi) {
    int mid = (lo + hi) >> 1;
    if (a[mid] < key) lo = mid + 1; else hi = mid;
  }
  return lo;
}

__global__ void k_pool(const float* __restrict__ X, const int* __restrict__ batch,
                       const float* __restrict__ tsc, const float* __restrict__ tsh,
                       float* __restrict__ z, int n) {
  int g = blockIdx.x;
  int c = threadIdx.x;  // 128
  __shared__ int slo, shi;
  if (c == 0) {
    slo = lb_i32(batch, n, g);
    shi = lb_i32(batch, n, g + 1);
  }
  __syncthreads();
  int lo = slo, hi = shi;
  float a = tsc[c], b = tsh[c];
  float s = 0.f, m = -3.402823466e38f;
  for (int i = lo; i < hi; ++i) {
    float v = fmaxf(0.f, X[(size_t)i * DD + c] * a + b);
    s += v;
    m = fmaxf(m, v);
  }
  float cntf = (float)(hi - lo);
  z[(size_t)g * 384 + c] = s;
  z[(size_t)g * 384 + 128 + c] = s / fmaxf(cntf, 1.f);
  z[(size_t)g * 384 + 256 + c] = m;
}

// ---------------- classifier head (fp32, tiny) ----------------

__global__ void k_cls1(const float* __restrict__ z, const float* __restrict__ cW1,
                       const float* __restrict__ cb1, float* __restrict__ z1,
                       float* __restrict__ colsum, float* __restrict__ colsq) {
  __shared__ float zr[384];
  int g = blockIdx.x;
  int c = threadIdx.x;  // 128
  for (int i = c; i < 384; i += 128) zr[i] = z[(size_t)g * 384 + i];
  __syncthreads();
  float s = cb1[c];
#pragma unroll 4
  for (int k = 0; k < 384; ++k) s = fmaf(zr[k], cW1[(size_t)k * 128 + c], s);
  z1[(size_t)g * 128 + c] = s;
  atomicAdd(&colsum[c], s);
  atomicAdd(&colsq[c], s * s);
}

__global__ void k_cls2(const float* __restrict__ z1, const float* __restrict__ csc,
                       const float* __restrict__ csh, const float* __restrict__ cW2,
                       const float* __restrict__ cb2, const float* __restrict__ cW3,
                       const float* __restrict__ cb3, float* __restrict__ out) {
  __shared__ float z1n[128];
  __shared__ float z2s[64];
  int g = blockIdx.x;
  int t = threadIdx.x;  // 128
  z1n[t] = fmaxf(0.f, z1[(size_t)g * 128 + t] * csc[t] + csh[t]);
  __syncthreads();
  if (t < 64) {
    float s = cb2[t];
#pragma unroll 4
    for (int k = 0; k < 128; ++k) s = fmaf(z1n[k], cW2[(size_t)k * 64 + t], s);
    z2s[t] = fmaxf(0.f, s);
  }
  __syncthreads();
  if (t < 2) {
    float s = cb3[t];
#pragma unroll 4
    for (int c = 0; c < 64; ++c) s = fmaf(z2s[c], cW3[(size_t)c * 2 + t], s);
    out[(size_t)g * 2 + t] = s;
  }
}

// ---------------- launch ----------------

extern "C" void kernel_launch(void* const* d_in, const int* in_sizes, int n_in,
                              void* d_out, int out_size, void* d_ws, size_t ws_size,
                              hipStream_t stream) {
  const float* x = (const float*)d_in[0];
  const int* ei = (const int*)d_in[1];     // int32 (harness downcasts int64)
  const int* batch = (const int*)d_in[2];  // int32
  const float* W1 = (const float*)d_in[4];
  const float* b1 = (const float*)d_in[5];
  const float* g1 = (const float*)d_in[6];
  const float* be1 = (const float*)d_in[7];
  const float* W2 = (const float*)d_in[8];
  const float* b2 = (const float*)d_in[9];
  const float* gbn = (const float*)d_in[10];
  const float* bbn = (const float*)d_in[11];
  const float* epsv = (const float*)d_in[12];
  const float* cW1 = (const float*)d_in[13];
  const float* cb1 = (const float*)d_in[14];
  const float* cg = (const float*)d_in[15];
  const float* cbeta = (const float*)d_in[16];
  const float* cW2 = (const float*)d_in[17];
  const float* cb2 = (const float*)d_in[18];
  const float* cW3 = (const float*)d_in[19];
  const float* cb3 = (const float*)d_in[20];
  float* out = (float*)d_out;

  char* p = (char*)d_ws;
  auto alloc = [&](size_t bytes) {
    char* r = p;
    p += (bytes + 255) & ~(size_t)255;
    return r;
  };
  int* cnt = (int*)alloc((size_t)NN * 4);
  int* rs = (int*)alloc((size_t)(NN + 1) * 4);
  int* cur = (int*)alloc((size_t)NN * 4);
  int* ci = (int*)alloc((size_t)EE * 4);
  int* part = (int*)alloc(128 * 4);
  int* partx = (int*)alloc(128 * 4);
  float* h0 = (float*)alloc((size_t)NN * DD * 4);
  float* h1 = (float*)alloc((size_t)NN * 2 * DD * 4);
  float* xp = (float*)alloc((size_t)NN * DD * 4);
  float* stats = (float*)alloc(512 * 4);  // colsum[256] + colsq[256]
  float* colsum = stats;
  float* colsq = stats + 256;
  float* tsc1 = (float*)alloc(256 * 4);
  float* tsh1 = (float*)alloc(256 * 4);
  float* tscX = (float*)alloc(128 * 4);
  float* tshX = (float*)alloc(128 * 4);
  float* zbuf = (float*)alloc((size_t)GG * 384 * 4);
  float* z1 = (float*)alloc((size_t)GG * 128 * 4);
  unsigned short* W1t = (unsigned short*)alloc((size_t)4 * 256 * 128 * 2);
  unsigned short* W2t = (unsigned short*)alloc((size_t)4 * 128 * 256 * 2);
  (void)ws_size; (void)n_in; (void)in_sizes; (void)out_size;

  // weight convert+transpose to bf16 (static across layers/calls)
  k_conv<<<512, 256, 0, stream>>>(W1, W2, W1t, W2t);

  // CSR build (edges static across layers)
  hipMemsetAsync(cnt, 0, (size_t)NN * 4, stream);
  k_hist<<<(EE + 255) / 256, 256, 0, stream>>>(ei, cnt);
  const int nscan = (NN + 1023) / 1024;  // 98
  k_part<<<nscan, 1024, 0, stream>>>(cnt, part);
  k_scanpart<<<1, 128, 0, stream>>>(part, partx, nscan);
  k_rs<<<nscan, 1024, 0, stream>>>(cnt, partx, rs, cur);
  k_fill<<<(EE + 255) / 256, 256, 0, stream>>>(ei, cur, ci);

  const int gx = (NN + GM - 1) / GM;  // 782
  const float* Xin = x;
  for (int l = 0; l < LL; ++l) {
    int mode = (l > 0) ? 1 : 0;
    k_agg<<<(NN * DD + 255) / 256, 256, 0, stream>>>(Xin, rs, ci, epsv, l, mode,
                                                     tscX, tshX, h0, NN);
    hipMemsetAsync(stats, 0, 512 * 4, stream);
    k_gemm_mfma<<<dim3(gx, 4), 256, 0, stream>>>(
        h0, 128, 0, nullptr, nullptr, W1t + (size_t)l * 256 * 128, 256,
        b1 + (size_t)l * 256, h1, colsum, colsq, NN);
    k_fin<<<1, 256, 0, stream>>>(colsum, colsq, g1 + (size_t)l * 256,
                                 be1 + (size_t)l * 256, tsc1, tsh1, 256, 1.0f / NN);
    hipMemsetAsync(stats, 0, 512 * 4, stream);
    k_gemm_mfma<<<dim3(gx, 2), 256, 0, stream>>>(
        h1, 256, 1, tsc1, tsh1, W2t + (size_t)l * 128 * 256, 128,
        b2 + (size_t)l * 128, xp, colsum, colsq, NN);
    k_fin<<<1, 256, 0, stream>>>(colsum, colsq, gbn + (size_t)l * 128,
                                 bbn + (size_t)l * 128, tscX, tshX, 128, 1.0f / NN);
    Xin = xp;
  }

  k_pool<<<GG, 128, 0, stream>>>(xp, batch, tscX, tshX, zbuf, NN);
  hipMemsetAsync(stats, 0, 512 * 4, stream);
  k_cls1<<<GG, 128, 0, stream>>>(zbuf, cW1, cb1, z1, colsum, colsq);
  k_fin<<<1, 256, 0, stream>>>(colsum, colsq, cg, cbeta, tscX, tshX, 128, 1.0f / GG);
  k_cls2<<<GG, 128, 0, stream>>>(z1, tscX, tshX, cW2, cb2, cW3, cb3, out);
}

// Round 6
// 1259.770 us; speedup vs baseline: 1.5107x; 1.1792x over previous
//
#include <hip/hip_runtime.h>
#include <cstdint>
#include <cstddef>

// Problem constants (fixed by the reference setup_inputs).
#define NN 100000
#define EE 500000
#define DD 128
#define GG 512
#define LL 4
#define BN_EPS 1e-5f

typedef __attribute__((ext_vector_type(8))) short short8;
typedef __attribute__((ext_vector_type(4))) float f32x4;

static __device__ __forceinline__ unsigned short f2bf(float f) {
  union { float f; unsigned u; } v;
  v.f = f;
  unsigned r = v.u + 0x7fffu + ((v.u >> 16) & 1u);  // RNE
  return (unsigned short)(r >> 16);
}

// ---------------- CSR build (int32 inputs) ----------------

__global__ void k_hist(const int* __restrict__ ei, int* __restrict__ cnt) {
  int e = blockIdx.x * 256 + threadIdx.x;
  if (e < EE) {
    int d = ei[EE + e];
    if (d >= 0 && d < NN) atomicAdd(&cnt[d], 1);
  }
}

__global__ void k_part(const int* __restrict__ cnt, int* __restrict__ part) {
  __shared__ int sm[1024];
  int t = threadIdx.x;
  int i = blockIdx.x * 1024 + t;
  sm[t] = (i < NN) ? cnt[i] : 0;
  __syncthreads();
  for (int off = 512; off > 0; off >>= 1) {
    if (t < off) sm[t] += sm[t + off];
    __syncthreads();
  }
  if (t == 0) part[blockIdx.x] = sm[0];
}

__global__ void k_scanpart(const int* __restrict__ part, int* __restrict__ partx, int nb) {
  __shared__ int sm[128];
  int t = threadIdx.x;
  int v = (t < nb) ? part[t] : 0;
  sm[t] = v;
  __syncthreads();
  for (int off = 1; off < 128; off <<= 1) {
    int u = (t >= off) ? sm[t - off] : 0;
    __syncthreads();
    sm[t] += u;
    __syncthreads();
  }
  if (t < nb) partx[t] = sm[t] - v;
}

__global__ void k_rs(const int* __restrict__ cnt, const int* __restrict__ partx,
                     int* __restrict__ rs, int* __restrict__ cur) {
  __shared__ int sm[1024];
  int t = threadIdx.x;
  int i = blockIdx.x * 1024 + t;
  int v = (i < NN) ? cnt[i] : 0;
  sm[t] = v;
  __syncthreads();
  for (int off = 1; off < 1024; off <<= 1) {
    int u = (t >= off) ? sm[t - off] : 0;
    __syncthreads();
    sm[t] += u;
    __syncthreads();
  }
  if (i < NN) {
    int excl = partx[blockIdx.x] + sm[t] - v;
    rs[i] = excl;
    cur[i] = excl;
    if (i == NN - 1) rs[NN] = excl + v;
  }
}

__global__ void k_fill(const int* __restrict__ ei, int* __restrict__ cur,
                       int* __restrict__ ci) {
  int e = blockIdx.x * 256 + threadIdx.x;
  if (e < EE) {
    int s = ei[e];
    int d = ei[EE + e];
    if (d >= 0 && d < NN && s >= 0 && s < NN) {
      int pos = atomicAdd(&cur[d], 1);
      if (pos >= 0 && pos < EE) ci[pos] = s;  // order irrelevant (sum)
    }
  }
}

// ---------------- weight convert: W -> W^T in bf16, once per call ----------------

__global__ void k_conv(const float* __restrict__ W1, const float* __restrict__ W2,
                       unsigned short* __restrict__ W1t, unsigned short* __restrict__ W2t) {
  int idx = blockIdx.x * 256 + threadIdx.x;
  if (idx < 4 * 256 * 128) {
    {  // W1: [l][k][nc] (K=128,NC=256) -> [l][nc][k]
      int l = idx >> 15, rem = idx & 32767;
      int nc = rem >> 7, k = rem & 127;
      W1t[idx] = f2bf(W1[(l << 15) + k * 256 + nc]);
    }
    {  // W2: [l][k][nc] (K=256,NC=128) -> [l][nc][k]
      int l = idx >> 15, rem = idx & 32767;
      int nc = rem >> 8, k = rem & 255;
      W2t[idx] = f2bf(W2[(l << 15) + k * 128 + nc]);
    }
  }
}

// ---------------- aggregation: h0 = (1+eps)*xn + sum_{nbrs} xn ----------------
// float4 per thread (32 threads/node). xn = mode ? relu(tsc*x+tsh) : x.

__global__ __launch_bounds__(256) void k_agg(
    const float* __restrict__ X, const int* __restrict__ rs,
    const int* __restrict__ ci, const float* __restrict__ epsv, int l, int mode,
    const float* __restrict__ tsc, const float* __restrict__ tsh,
    float* __restrict__ h0, int n) {
  int idx = blockIdx.x * 256 + threadIdx.x;
  int node = idx >> 5;
  int c4 = (idx & 31) << 2;
  if (node >= n) return;
  float4 a = make_float4(1.f, 1.f, 1.f, 1.f);
  float4 b = make_float4(0.f, 0.f, 0.f, 0.f);
  if (mode) {
    a = *(const float4*)(tsc + c4);
    b = *(const float4*)(tsh + c4);
  }
  float4 v = *(const float4*)(X + (size_t)node * DD + c4);
  if (mode) {
    v.x = fmaxf(0.f, v.x * a.x + b.x);
    v.y = fmaxf(0.f, v.y * a.y + b.y);
    v.z = fmaxf(0.f, v.z * a.z + b.z);
    v.w = fmaxf(0.f, v.w * a.w + b.w);
  }
  float se = 1.f + epsv[l];
  float4 acc;
  acc.x = se * v.x; acc.y = se * v.y; acc.z = se * v.z; acc.w = se * v.w;
  int e0 = rs[node], e1 = rs[node + 1];
  int nb = (e0 < e1) ? ci[e0] : 0;
  for (int j = e0; j < e1; ++j) {
    int nb_next = (j + 1 < e1) ? ci[j + 1] : 0;  // prefetch next index
    float4 u = *(const float4*)(X + (size_t)nb * DD + c4);
    if (mode) {
      u.x = fmaxf(0.f, u.x * a.x + b.x);
      u.y = fmaxf(0.f, u.y * a.y + b.y);
      u.z = fmaxf(0.f, u.z * a.z + b.z);
      u.w = fmaxf(0.f, u.w * a.w + b.w);
    }
    acc.x += u.x; acc.y += u.y; acc.z += u.z; acc.w += u.w;
    nb = nb_next;
  }
  *(float4*)(h0 + (size_t)node * DD + c4) = acc;
}

// ---------------- MFMA bf16 GEMM, full-K A panel in LDS, internal col-tile loop ----
// C = xform(A) @ Bt^T + bias, with per-column (sum,sumsq) stats.
// A staged ONCE per row-block (bf16, transform applied), then loop over NC/64
// column tiles. 256 threads = 4 waves.

template <int K, int NC, int GM>
__global__ __launch_bounds__(256) void k_gemm_full(
    const float* __restrict__ A, int mode, const float* __restrict__ tsc,
    const float* __restrict__ tsh, const unsigned short* __restrict__ Bt,
    const float* __restrict__ bias, float* __restrict__ C,
    float* __restrict__ colsum, float* __restrict__ colsq, int n) {
  constexpr int KP = K + 8;         // padded row stride (ushorts); (K+8)*2 is 16B-mult
  constexpr int RPW = GM / 4;       // rows per wave
  constexpr int RF = GM / 64;       // 16-row frags per wave (2 for GM=128, 1 for GM=64)
  constexpr int NT = NC / 64;       // column tiles
  __shared__ unsigned short As[GM][KP];
  __shared__ unsigned short Bs[64][KP];
  __shared__ float bsum[64], bsq[64];
  int tid = threadIdx.x;
  int lane = tid & 63, wave = tid >> 6;
  int quad = lane >> 4, l15 = lane & 15;
  int row0 = blockIdx.x * GM;

  // stage A panel: GM x K fp32 -> transform -> bf16. GM*K/1024 float4 per thread.
#pragma unroll
  for (int it = 0; it < GM * K / 1024; ++it) {
    int f = tid + it * 256;
    int r = f / (K / 4);
    int kq = (f % (K / 4)) * 4;
    int gr = row0 + r;
    float4 v = make_float4(0.f, 0.f, 0.f, 0.f);
    if (gr < n) v = *(const float4*)(A + (size_t)gr * K + kq);
    if (mode) {
      v.x = fmaxf(0.f, v.x * tsc[kq + 0] + tsh[kq + 0]);
      v.y = fmaxf(0.f, v.y * tsc[kq + 1] + tsh[kq + 1]);
      v.z = fmaxf(0.f, v.z * tsc[kq + 2] + tsh[kq + 2]);
      v.w = fmaxf(0.f, v.w * tsc[kq + 3] + tsh[kq + 3]);
    }
    ushort4 o;
    o.x = f2bf(v.x); o.y = f2bf(v.y); o.z = f2bf(v.z); o.w = f2bf(v.w);
    *(ushort4*)(&As[r][kq]) = o;
  }

  for (int ct = 0; ct < NT; ++ct) {
    int col0 = ct * 64;
    __syncthreads();  // As ready (iter 0); prior epilogue done with Bs/bsum
    // stage B tile: 64 cols x K bf16 (contiguous in k). 64*K/2048 uint4/thread.
#pragma unroll
    for (int it = 0; it < 64 * K / 2048; ++it) {
      int idx = tid + it * 256;
      int r = idx / (K / 8);
      int c8 = (idx % (K / 8)) * 8;
      *(uint4*)(&Bs[r][c8]) = *(const uint4*)(Bt + (size_t)(col0 + r) * K + c8);
    }
    if (tid < 64) { bsum[tid] = 0.f; bsq[tid] = 0.f; }
    __syncthreads();

    f32x4 acc[RF][4];
#pragma unroll
    for (int i = 0; i < RF; ++i)
#pragma unroll
      for (int j = 0; j < 4; ++j) acc[i][j] = (f32x4){0.f, 0.f, 0.f, 0.f};

#pragma unroll
    for (int kk = 0; kk < K; kk += 32) {
      int ko = kk + quad * 8;
      short8 b0 = *(const short8*)(&Bs[l15][ko]);
      short8 b1 = *(const short8*)(&Bs[16 + l15][ko]);
      short8 b2 = *(const short8*)(&Bs[32 + l15][ko]);
      short8 b3 = *(const short8*)(&Bs[48 + l15][ko]);
#pragma unroll
      for (int rf = 0; rf < RF; ++rf) {
        short8 av = *(const short8*)(&As[wave * RPW + rf * 16 + l15][ko]);
        acc[rf][0] = __builtin_amdgcn_mfma_f32_16x16x32_bf16(av, b0, acc[rf][0], 0, 0, 0);
        acc[rf][1] = __builtin_amdgcn_mfma_f32_16x16x32_bf16(av, b1, acc[rf][1], 0, 0, 0);
        acc[rf][2] = __builtin_amdgcn_mfma_f32_16x16x32_bf16(av, b2, acc[rf][2], 0, 0, 0);
        acc[rf][3] = __builtin_amdgcn_mfma_f32_16x16x32_bf16(av, b3, acc[rf][3], 0, 0, 0);
      }
    }

    // epilogue: bias, C store (fp32), stats. C/D layout: col=l15, row=quad*4+reg.
    float s4[4] = {0.f, 0.f, 0.f, 0.f}, q4[4] = {0.f, 0.f, 0.f, 0.f};
#pragma unroll
    for (int cf = 0; cf < 4; ++cf) {
      int col = col0 + cf * 16 + l15;
      float bv = bias[col];
#pragma unroll
      for (int rf = 0; rf < RF; ++rf) {
        int rbase = row0 + wave * RPW + rf * 16 + quad * 4;
#pragma unroll
        for (int reg = 0; reg < 4; ++reg) {
          int gr = rbase + reg;
          if (gr < n) {
            float e = acc[rf][cf][reg] + bv;
            C[(size_t)gr * NC + col] = e;
            s4[cf] += e;
            q4[cf] += e * e;
          }
        }
      }
    }
#pragma unroll
    for (int cf = 0; cf < 4; ++cf) {
      s4[cf] += __shfl_xor(s4[cf], 16, 64);
      s4[cf] += __shfl_xor(s4[cf], 32, 64);
      q4[cf] += __shfl_xor(q4[cf], 16, 64);
      q4[cf] += __shfl_xor(q4[cf], 32, 64);
    }
    if (quad == 0) {
#pragma unroll
      for (int cf = 0; cf < 4; ++cf) {
        atomicAdd(&bsum[cf * 16 + l15], s4[cf]);
        atomicAdd(&bsq[cf * 16 + l15], q4[cf]);
      }
    }
    __syncthreads();
    if (tid < 64) {
      atomicAdd(&colsum[col0 + tid], bsum[tid]);
      atomicAdd(&colsq[col0 + tid], bsq[tid]);
    }
  }
}

// ---------------- BN stat finalize: per-column scale/shift ----------------

__global__ void k_fin(const float* __restrict__ colsum, const float* __restrict__ colsq,
                      const float* __restrict__ g, const float* __restrict__ be,
                      float* __restrict__ osc, float* __restrict__ osh, int nc,
                      float invn) {
  int c = threadIdx.x;
  if (c < nc) {
    float m = colsum[c] * invn;
    float v = fmaxf(colsq[c] * invn - m * m, 0.f);
    float sc = g[c] * rsqrtf(v + BN_EPS);
    osc[c] = sc;
    osh[c] = be[c] - m * sc;
  }
}

// ---------------- pooling (batch sorted -> contiguous ranges) ----------------

static __device__ __forceinline__ int lb_i32(const int* a, int n, int key) {
  int lo = 0, hi = n;
  while (lo < hi) {
    int mid = (lo + hi) >> 1;
    if (a[mid] < key) lo = mid + 1; else hi = mid;
  }
  return lo;
}

__global__ void k_pool(const float* __restrict__ X, const int* __restrict__ batch,
                       const float* __restrict__ tsc, const float* __restrict__ tsh,
                       float* __restrict__ z, int n) {
  int g = blockIdx.x;
  int c = threadIdx.x;  // 128
  __shared__ int slo, shi;
  if (c == 0) {
    slo = lb_i32(batch, n, g);
    shi = lb_i32(batch, n, g + 1);
  }
  __syncthreads();
  int lo = slo, hi = shi;
  float a = tsc[c], b = tsh[c];
  float s = 0.f, m = -3.402823466e38f;
  for (int i = lo; i < hi; ++i) {
    float v = fmaxf(0.f, X[(size_t)i * DD + c] * a + b);
    s += v;
    m = fmaxf(m, v);
  }
  float cntf = (float)(hi - lo);
  z[(size_t)g * 384 + c] = s;
  z[(size_t)g * 384 + 128 + c] = s / fmaxf(cntf, 1.f);
  z[(size_t)g * 384 + 256 + c] = m;
}

// ---------------- classifier head (fp32, tiny) ----------------

__global__ void k_cls1(const float* __restrict__ z, const float* __restrict__ cW1,
                       const float* __restrict__ cb1, float* __restrict__ z1,
                       float* __restrict__ colsum, float* __restrict__ colsq) {
  __shared__ float zr[384];
  int g = blockIdx.x;
  int c = threadIdx.x;  // 128
  for (int i = c; i < 384; i += 128) zr[i] = z[(size_t)g * 384 + i];
  __syncthreads();
  float s = cb1[c];
#pragma unroll 4
  for (int k = 0; k < 384; ++k) s = fmaf(zr[k], cW1[(size_t)k * 128 + c], s);
  z1[(size_t)g * 128 + c] = s;
  atomicAdd(&colsum[c], s);
  atomicAdd(&colsq[c], s * s);
}

__global__ void k_cls2(const float* __restrict__ z1, const float* __restrict__ csc,
                       const float* __restrict__ csh, const float* __restrict__ cW2,
                       const float* __restrict__ cb2, const float* __restrict__ cW3,
                       const float* __restrict__ cb3, float* __restrict__ out) {
  __shared__ float z1n[128];
  __shared__ float z2s[64];
  int g = blockIdx.x;
  int t = threadIdx.x;  // 128
  z1n[t] = fmaxf(0.f, z1[(size_t)g * 128 + t] * csc[t] + csh[t]);
  __syncthreads();
  if (t < 64) {
    float s = cb2[t];
#pragma unroll 4
    for (int k = 0; k < 128; ++k) s = fmaf(z1n[k], cW2[(size_t)k * 64 + t], s);
    z2s[t] = fmaxf(0.f, s);
  }
  __syncthreads();
  if (t < 2) {
    float s = cb3[t];
#pragma unroll 4
    for (int c = 0; c < 64; ++c) s = fmaf(z2s[c], cW3[(size_t)c * 2 + t], s);
    out[(size_t)g * 2 + t] = s;
  }
}

// ---------------- launch ----------------

extern "C" void kernel_launch(void* const* d_in, const int* in_sizes, int n_in,
                              void* d_out, int out_size, void* d_ws, size_t ws_size,
                              hipStream_t stream) {
  const float* x = (const float*)d_in[0];
  const int* ei = (const int*)d_in[1];     // int32 (harness downcasts int64)
  const int* batch = (const int*)d_in[2];  // int32
  const float* W1 = (const float*)d_in[4];
  const float* b1 = (const float*)d_in[5];
  const float* g1 = (const float*)d_in[6];
  const float* be1 = (const float*)d_in[7];
  const float* W2 = (const float*)d_in[8];
  const float* b2 = (const float*)d_in[9];
  const float* gbn = (const float*)d_in[10];
  const float* bbn = (const float*)d_in[11];
  const float* epsv = (const float*)d_in[12];
  const float* cW1 = (const float*)d_in[13];
  const float* cb1 = (const float*)d_in[14];
  const float* cg = (const float*)d_in[15];
  const float* cbeta = (const float*)d_in[16];
  const float* cW2 = (const float*)d_in[17];
  const float* cb2 = (const float*)d_in[18];
  const float* cW3 = (const float*)d_in[19];
  const float* cb3 = (const float*)d_in[20];
  float* out = (float*)d_out;

  char* p = (char*)d_ws;
  auto alloc = [&](size_t bytes) {
    char* r = p;
    p += (bytes + 255) & ~(size_t)255;
    return r;
  };
  int* cnt = (int*)alloc((size_t)NN * 4);
  int* rs = (int*)alloc((size_t)(NN + 1) * 4);
  int* cur = (int*)alloc((size_t)NN * 4);
  int* ci = (int*)alloc((size_t)EE * 4);
  int* part = (int*)alloc(128 * 4);
  int* partx = (int*)alloc(128 * 4);
  float* h0 = (float*)alloc((size_t)NN * DD * 4);
  float* h1 = (float*)alloc((size_t)NN * 2 * DD * 4);
  float* xp = (float*)alloc((size_t)NN * DD * 4);
  float* stats = (float*)alloc(512 * 4);  // colsum[256] + colsq[256]
  float* colsum = stats;
  float* colsq = stats + 256;
  float* tsc1 = (float*)alloc(256 * 4);
  float* tsh1 = (float*)alloc(256 * 4);
  float* tscX = (float*)alloc(128 * 4);
  float* tshX = (float*)alloc(128 * 4);
  float* zbuf = (float*)alloc((size_t)GG * 384 * 4);
  float* z1 = (float*)alloc((size_t)GG * 128 * 4);
  unsigned short* W1t = (unsigned short*)alloc((size_t)4 * 256 * 128 * 2);
  unsigned short* W2t = (unsigned short*)alloc((size_t)4 * 128 * 256 * 2);
  (void)ws_size; (void)n_in; (void)in_sizes; (void)out_size;

  // weight convert+transpose to bf16 (static across layers/calls)
  k_conv<<<512, 256, 0, stream>>>(W1, W2, W1t, W2t);

  // CSR build (edges static across layers)
  hipMemsetAsync(cnt, 0, (size_t)NN * 4, stream);
  k_hist<<<(EE + 255) / 256, 256, 0, stream>>>(ei, cnt);
  const int nscan = (NN + 1023) / 1024;  // 98
  k_part<<<nscan, 1024, 0, stream>>>(cnt, part);
  k_scanpart<<<1, 128, 0, stream>>>(part, partx, nscan);
  k_rs<<<nscan, 1024, 0, stream>>>(cnt, partx, rs, cur);
  k_fill<<<(EE + 255) / 256, 256, 0, stream>>>(ei, cur, ci);

  const float* Xin = x;
  for (int l = 0; l < LL; ++l) {
    int mode = (l > 0) ? 1 : 0;
    k_agg<<<(NN * 32 + 255) / 256, 256, 0, stream>>>(Xin, rs, ci, epsv, l, mode,
                                                     tscX, tshX, h0, NN);
    hipMemsetAsync(stats, 0, 512 * 4, stream);
    k_gemm_full<128, 256, 128><<<(NN + 127) / 128, 256, 0, stream>>>(
        h0, 0, nullptr, nullptr, W1t + (size_t)l * 256 * 128,
        b1 + (size_t)l * 256, h1, colsum, colsq, NN);
    k_fin<<<1, 256, 0, stream>>>(colsum, colsq, g1 + (size_t)l * 256,
                                 be1 + (size_t)l * 256, tsc1, tsh1, 256, 1.0f / NN);
    hipMemsetAsync(stats, 0, 512 * 4, stream);
    k_gemm_full<256, 128, 64><<<(NN + 63) / 64, 256, 0, stream>>>(
        h1, 1, tsc1, tsh1, W2t + (size_t)l * 128 * 256,
        b2 + (size_t)l * 128, xp, colsum, colsq, NN);
    k_fin<<<1, 256, 0, stream>>>(colsum, colsq, gbn + (size_t)l * 128,
                                 bbn + (size_t)l * 128, tscX, tshX, 128, 1.0f / NN);
    Xin = xp;
  }

  k_pool<<<GG, 128, 0, stream>>>(xp, batch, tscX, tshX, zbuf, NN);
  hipMemsetAsync(stats, 0, 512 * 4, stream);
  k_cls1<<<GG, 128, 0, stream>>>(zbuf, cW1, cb1, z1, colsum, colsq);
  k_fin<<<1, 256, 0, stream>>>(colsum, colsq, cg, cbeta, tscX, tshX, 128, 1.0f / GG);
  k_cls2<<<GG, 128, 0, stream>>>(z1, tscX, tshX, cW2, cb2, cW3, cb3, out);
}

// Round 7
// 1046.036 us; speedup vs baseline: 1.8194x; 1.2043x over previous
//
#include <hip/hip_runtime.h>
#include <cstdint>
#include <cstddef>

// Problem constants (fixed by the reference setup_inputs).
#define NN 100000
#define EE 500000
#define DD 128
#define GG 512
#define LL 4
#define BN_EPS 1e-5f

typedef __attribute__((ext_vector_type(8))) short short8;
typedef __attribute__((ext_vector_type(8))) unsigned short ushort8v;
typedef __attribute__((ext_vector_type(4))) float f32x4;

static __device__ __forceinline__ unsigned short f2bf(float f) {
  union { float f; unsigned u; } v;
  v.f = f;
  unsigned r = v.u + 0x7fffu + ((v.u >> 16) & 1u);  // RNE
  return (unsigned short)(r >> 16);
}
static __device__ __forceinline__ float bf2f(unsigned short u) {
  union { unsigned u; float f; } v;
  v.u = ((unsigned)u) << 16;
  return v.f;
}

// ---------------- CSR build (int32 inputs) ----------------

__global__ void k_hist(const int* __restrict__ ei, int* __restrict__ cnt) {
  int e = blockIdx.x * 256 + threadIdx.x;
  if (e < EE) {
    int d = ei[EE + e];
    if (d >= 0 && d < NN) atomicAdd(&cnt[d], 1);
  }
}

__global__ void k_part(const int* __restrict__ cnt, int* __restrict__ part) {
  __shared__ int sm[1024];
  int t = threadIdx.x;
  int i = blockIdx.x * 1024 + t;
  sm[t] = (i < NN) ? cnt[i] : 0;
  __syncthreads();
  for (int off = 512; off > 0; off >>= 1) {
    if (t < off) sm[t] += sm[t + off];
    __syncthreads();
  }
  if (t == 0) part[blockIdx.x] = sm[0];
}

__global__ void k_scanpart(const int* __restrict__ part, int* __restrict__ partx, int nb) {
  __shared__ int sm[128];
  int t = threadIdx.x;
  int v = (t < nb) ? part[t] : 0;
  sm[t] = v;
  __syncthreads();
  for (int off = 1; off < 128; off <<= 1) {
    int u = (t >= off) ? sm[t - off] : 0;
    __syncthreads();
    sm[t] += u;
    __syncthreads();
  }
  if (t < nb) partx[t] = sm[t] - v;
}

__global__ void k_rs(const int* __restrict__ cnt, const int* __restrict__ partx,
                     int* __restrict__ rs, int* __restrict__ cur) {
  __shared__ int sm[1024];
  int t = threadIdx.x;
  int i = blockIdx.x * 1024 + t;
  int v = (i < NN) ? cnt[i] : 0;
  sm[t] = v;
  __syncthreads();
  for (int off = 1; off < 1024; off <<= 1) {
    int u = (t >= off) ? sm[t - off] : 0;
    __syncthreads();
    sm[t] += u;
    __syncthreads();
  }
  if (i < NN) {
    int excl = partx[blockIdx.x] + sm[t] - v;
    rs[i] = excl;
    cur[i] = excl;
    if (i == NN - 1) rs[NN] = excl + v;
  }
}

__global__ void k_fill(const int* __restrict__ ei, int* __restrict__ cur,
                       int* __restrict__ ci) {
  int e = blockIdx.x * 256 + threadIdx.x;
  if (e < EE) {
    int s = ei[e];
    int d = ei[EE + e];
    if (d >= 0 && d < NN && s >= 0 && s < NN) {
      int pos = atomicAdd(&cur[d], 1);
      if (pos >= 0 && pos < EE) ci[pos] = s;  // order irrelevant (sum)
    }
  }
}

// ---------------- weight convert: W -> W^T in bf16, once per call ----------------

__global__ void k_conv(const float* __restrict__ W1, const float* __restrict__ W2,
                       unsigned short* __restrict__ W1t, unsigned short* __restrict__ W2t) {
  int idx = blockIdx.x * 256 + threadIdx.x;
  if (idx < 4 * 256 * 128) {
    {  // W1: [l][k][nc] (K=128,NC=256) -> [l][nc][k]
      int l = idx >> 15, rem = idx & 32767;
      int nc = rem >> 7, k = rem & 127;
      W1t[idx] = f2bf(W1[(l << 15) + k * 256 + nc]);
    }
    {  // W2: [l][k][nc] (K=256,NC=128) -> [l][nc][k]
      int l = idx >> 15, rem = idx & 32767;
      int nc = rem >> 8, k = rem & 255;
      W2t[idx] = f2bf(W2[(l << 15) + k * 128 + nc]);
    }
  }
}

// ---------------- aggregation (layer 0): fp32 x in, bf16 h0 out ----------------
// 32 lanes/node, float4.

__global__ __launch_bounds__(256) void k_agg_f32(
    const float* __restrict__ X, const int* __restrict__ rs,
    const int* __restrict__ ci, const float* __restrict__ epsv,
    unsigned short* __restrict__ h0, int n) {
  int idx = blockIdx.x * 256 + threadIdx.x;
  int node = idx >> 5;
  int c4 = (idx & 31) << 2;
  if (node >= n) return;
  float4 v = *(const float4*)(X + (size_t)node * DD + c4);
  float se = 1.f + epsv[0];
  float4 acc;
  acc.x = se * v.x; acc.y = se * v.y; acc.z = se * v.z; acc.w = se * v.w;
  int e0 = rs[node], e1 = rs[node + 1];
  for (int j = e0; j < e1; ++j) {
    int nb = ci[j];
    float4 u = *(const float4*)(X + (size_t)nb * DD + c4);
    acc.x += u.x; acc.y += u.y; acc.z += u.z; acc.w += u.w;
  }
  ushort4 o;
  o.x = f2bf(acc.x); o.y = f2bf(acc.y); o.z = f2bf(acc.z); o.w = f2bf(acc.w);
  *(ushort4*)(h0 + (size_t)node * DD + c4) = o;
}

// ---------------- aggregation (layers 1+): bf16 X in (+BN/ReLU), bf16 h0 out ----
// 16 lanes/node, ushort8 (16B) loads.

__global__ __launch_bounds__(256) void k_agg_bf16(
    const unsigned short* __restrict__ X, const int* __restrict__ rs,
    const int* __restrict__ ci, const float* __restrict__ epsv, int l,
    const float* __restrict__ tsc, const float* __restrict__ tsh,
    unsigned short* __restrict__ h0, int n) {
  int idx = blockIdx.x * 256 + threadIdx.x;
  int node = idx >> 4;
  int c8 = (idx & 15) << 3;
  if (node >= n) return;
  float4 a0 = *(const float4*)(tsc + c8), a1 = *(const float4*)(tsc + c8 + 4);
  float4 b0 = *(const float4*)(tsh + c8), b1 = *(const float4*)(tsh + c8 + 4);
  float sa[8] = {a0.x, a0.y, a0.z, a0.w, a1.x, a1.y, a1.z, a1.w};
  float sb[8] = {b0.x, b0.y, b0.z, b0.w, b1.x, b1.y, b1.z, b1.w};
  float se = 1.f + epsv[l];
  ushort8v v = *(const ushort8v*)(X + (size_t)node * DD + c8);
  float acc[8];
#pragma unroll
  for (int j = 0; j < 8; ++j)
    acc[j] = se * fmaxf(0.f, bf2f(v[j]) * sa[j] + sb[j]);
  int e0 = rs[node], e1 = rs[node + 1];
  for (int e = e0; e < e1; ++e) {
    int nb = ci[e];
    ushort8v u = *(const ushort8v*)(X + (size_t)nb * DD + c8);
#pragma unroll
    for (int j = 0; j < 8; ++j)
      acc[j] += fmaxf(0.f, bf2f(u[j]) * sa[j] + sb[j]);
  }
  ushort8v o;
#pragma unroll
  for (int j = 0; j < 8; ++j) o[j] = f2bf(acc[j]);
  *(ushort8v*)(h0 + (size_t)node * DD + c8) = o;
}

// ---------------- MFMA bf16 GEMM: bf16 A (opt. BN/ReLU on read), bf16 C out ------
// GM=128 rows/block, 512 threads = 8 waves x 16 rows. Col-groups of 128 (8 frags
// per wave), K-chunks of 128. GEMM1<128,256>: A staged once, 2 col-groups.
// GEMM2<256,128>: 1 col-group, 2 K-chunks. Per-column (sum,sumsq) stats fp32.

#define KCP 136  // padded chunk row stride (ushorts), 272B = 16B-mult

template <int K, int NC>
__global__ __launch_bounds__(512) void k_gemm(
    const unsigned short* __restrict__ A, int mode, const float* __restrict__ tsc,
    const float* __restrict__ tsh, const unsigned short* __restrict__ Bt,
    const float* __restrict__ bias, unsigned short* __restrict__ C,
    float* __restrict__ colsum, float* __restrict__ colsq, int n) {
  constexpr int KT = K / 128;   // k-chunks
  constexpr int NT = NC / 128;  // col-groups
  __shared__ unsigned short As[128][KCP];
  __shared__ unsigned short Bs[128][KCP];
  __shared__ float bsum[128], bsq[128];
  int tid = threadIdx.x;
  int lane = tid & 63, wave = tid >> 6;
  int quad = lane >> 4, l15 = lane & 15;
  int row0 = blockIdx.x * 128;

  for (int cg = 0; cg < NT; ++cg) {
    f32x4 acc[8];
#pragma unroll
    for (int j = 0; j < 8; ++j) acc[j] = (f32x4){0.f, 0.f, 0.f, 0.f};

    for (int kc = 0; kc < KT; ++kc) {
      __syncthreads();  // protect LDS reuse across chunks / col-groups
      if (cg == 0 || KT > 1) {
        // stage A chunk: 128 rows x 128 k bf16 (transform if mode)
#pragma unroll
        for (int it = 0; it < 4; ++it) {
          int f = tid + it * 512;
          int r = f >> 4;
          int c8 = (f & 15) << 3;
          int gr = row0 + r;
          ushort8v v = (ushort8v){0, 0, 0, 0, 0, 0, 0, 0};
          if (gr < n) v = *(const ushort8v*)(A + (size_t)gr * K + kc * 128 + c8);
          if (mode) {
            int kg = kc * 128 + c8;
            float4 s0 = *(const float4*)(tsc + kg);
            float4 s1 = *(const float4*)(tsc + kg + 4);
            float4 h0v = *(const float4*)(tsh + kg);
            float4 h1v = *(const float4*)(tsh + kg + 4);
            float sa[8] = {s0.x, s0.y, s0.z, s0.w, s1.x, s1.y, s1.z, s1.w};
            float sb[8] = {h0v.x, h0v.y, h0v.z, h0v.w, h1v.x, h1v.y, h1v.z, h1v.w};
#pragma unroll
            for (int j = 0; j < 8; ++j)
              v[j] = f2bf(fmaxf(0.f, bf2f(v[j]) * sa[j] + sb[j]));
          }
          *(ushort8v*)(&As[r][c8]) = v;
        }
      }
      // stage B: cols cg*128..+127, k chunk kc*128..+127
#pragma unroll
      for (int it = 0; it < 4; ++it) {
        int f = tid + it * 512;
        int r = f >> 4;
        int c8 = (f & 15) << 3;
        *(ushort8v*)(&Bs[r][c8]) =
            *(const ushort8v*)(Bt + (size_t)(cg * 128 + r) * K + kc * 128 + c8);
      }
      if (kc == 0 && tid < 128) { bsum[tid] = 0.f; bsq[tid] = 0.f; }
      __syncthreads();

#pragma unroll
      for (int kk = 0; kk < 128; kk += 32) {
        int ko = kk + quad * 8;
        short8 av = *(const short8*)(&As[wave * 16 + l15][ko]);
#pragma unroll
        for (int cf = 0; cf < 8; ++cf) {
          short8 bv = *(const short8*)(&Bs[cf * 16 + l15][ko]);
          acc[cf] = __builtin_amdgcn_mfma_f32_16x16x32_bf16(av, bv, acc[cf], 0, 0, 0);
        }
      }
    }

    // epilogue: bias, bf16 C store, fp32 stats. C/D: col=l15, row=quad*4+reg.
    float s8[8], q8[8];
#pragma unroll
    for (int j = 0; j < 8; ++j) { s8[j] = 0.f; q8[j] = 0.f; }
    int rbase = row0 + wave * 16 + quad * 4;
#pragma unroll
    for (int cf = 0; cf < 8; ++cf) {
      int col = cg * 128 + cf * 16 + l15;
      float bv = bias[col];
#pragma unroll
      for (int reg = 0; reg < 4; ++reg) {
        int gr = rbase + reg;
        if (gr < n) {
          float e = acc[cf][reg] + bv;
          C[(size_t)gr * NC + col] = f2bf(e);
          s8[cf] += e;
          q8[cf] += e * e;
        }
      }
    }
#pragma unroll
    for (int cf = 0; cf < 8; ++cf) {
      s8[cf] += __shfl_xor(s8[cf], 16, 64);
      s8[cf] += __shfl_xor(s8[cf], 32, 64);
      q8[cf] += __shfl_xor(q8[cf], 16, 64);
      q8[cf] += __shfl_xor(q8[cf], 32, 64);
    }
    if (quad == 0) {
#pragma unroll
      for (int cf = 0; cf < 8; ++cf) {
        atomicAdd(&bsum[cf * 16 + l15], s8[cf]);
        atomicAdd(&bsq[cf * 16 + l15], q8[cf]);
      }
    }
    __syncthreads();
    if (tid < 128) {
      atomicAdd(&colsum[cg * 128 + tid], bsum[tid]);
      atomicAdd(&colsq[cg * 128 + tid], bsq[tid]);
    }
  }
}

// ---------------- BN stat finalize: per-column scale/shift ----------------

__global__ void k_fin(const float* __restrict__ colsum, const float* __restrict__ colsq,
                      const float* __restrict__ g, const float* __restrict__ be,
                      float* __restrict__ osc, float* __restrict__ osh, int nc,
                      float invn) {
  int c = threadIdx.x;
  if (c < nc) {
    float m = colsum[c] * invn;
    float v = fmaxf(colsq[c] * invn - m * m, 0.f);
    float sc = g[c] * rsqrtf(v + BN_EPS);
    osc[c] = sc;
    osh[c] = be[c] - m * sc;
  }
}

// ---------------- pooling (batch sorted -> contiguous ranges), bf16 X ------------

static __device__ __forceinline__ int lb_i32(const int* a, int n, int key) {
  int lo = 0, hi = n;
  while (lo < hi) {
    int mid = (lo + hi) >> 1;
    if (a[mid] < key) lo = mid + 1; else hi = mid;
  }
  return lo;
}

__global__ void k_pool(const unsigned short* __restrict__ X, const int* __restrict__ batch,
                       const float* __restrict__ tsc, const float* __restrict__ tsh,
                       float* __restrict__ z, int n) {
  int g = blockIdx.x;
  int c = threadIdx.x;  // 128
  __shared__ int slo, shi;
  if (c == 0) {
    slo = lb_i32(batch, n, g);
    shi = lb_i32(batch, n, g + 1);
  }
  __syncthreads();
  int lo = slo, hi = shi;
  float a = tsc[c], b = tsh[c];
  float s = 0.f, m = -3.402823466e38f;
  for (int i = lo; i < hi; ++i) {
    float v = fmaxf(0.f, bf2f(X[(size_t)i * DD + c]) * a + b);
    s += v;
    m = fmaxf(m, v);
  }
  float cntf = (float)(hi - lo);
  z[(size_t)g * 384 + c] = s;
  z[(size_t)g * 384 + 128 + c] = s / fmaxf(cntf, 1.f);
  z[(size_t)g * 384 + 256 + c] = m;
}

// ---------------- classifier head (fp32, tiny) ----------------

__global__ void k_cls1(const float* __restrict__ z, const float* __restrict__ cW1,
                       const float* __restrict__ cb1, float* __restrict__ z1,
                       float* __restrict__ colsum, float* __restrict__ colsq) {
  __shared__ float zr[384];
  int g = blockIdx.x;
  int c = threadIdx.x;  // 128
  for (int i = c; i < 384; i += 128) zr[i] = z[(size_t)g * 384 + i];
  __syncthreads();
  float s = cb1[c];
#pragma unroll 4
  for (int k = 0; k < 384; ++k) s = fmaf(zr[k], cW1[(size_t)k * 128 + c], s);
  z1[(size_t)g * 128 + c] = s;
  atomicAdd(&colsum[c], s);
  atomicAdd(&colsq[c], s * s);
}

__global__ void k_cls2(const float* __restrict__ z1, const float* __restrict__ csc,
                       const float* __restrict__ csh, const float* __restrict__ cW2,
                       const float* __restrict__ cb2, const float* __restrict__ cW3,
                       const float* __restrict__ cb3, float* __restrict__ out) {
  __shared__ float z1n[128];
  __shared__ float z2s[64];
  int g = blockIdx.x;
  int t = threadIdx.x;  // 128
  z1n[t] = fmaxf(0.f, z1[(size_t)g * 128 + t] * csc[t] + csh[t]);
  __syncthreads();
  if (t < 64) {
    float s = cb2[t];
#pragma unroll 4
    for (int k = 0; k < 128; ++k) s = fmaf(z1n[k], cW2[(size_t)k * 64 + t], s);
    z2s[t] = fmaxf(0.f, s);
  }
  __syncthreads();
  if (t < 2) {
    float s = cb3[t];
#pragma unroll 4
    for (int c = 0; c < 64; ++c) s = fmaf(z2s[c], cW3[(size_t)c * 2 + t], s);
    out[(size_t)g * 2 + t] = s;
  }
}

// ---------------- launch ----------------

extern "C" void kernel_launch(void* const* d_in, const int* in_sizes, int n_in,
                              void* d_out, int out_size, void* d_ws, size_t ws_size,
                              hipStream_t stream) {
  const float* x = (const float*)d_in[0];
  const int* ei = (const int*)d_in[1];     // int32 (harness downcasts int64)
  const int* batch = (const int*)d_in[2];  // int32
  const float* W1 = (const float*)d_in[4];
  const float* b1 = (const float*)d_in[5];
  const float* g1 = (const float*)d_in[6];
  const float* be1 = (const float*)d_in[7];
  const float* W2 = (const float*)d_in[8];
  const float* b2 = (const float*)d_in[9];
  const float* gbn = (const float*)d_in[10];
  const float* bbn = (const float*)d_in[11];
  const float* epsv = (const float*)d_in[12];
  const float* cW1 = (const float*)d_in[13];
  const float* cb1 = (const float*)d_in[14];
  const float* cg = (const float*)d_in[15];
  const float* cbeta = (const float*)d_in[16];
  const float* cW2 = (const float*)d_in[17];
  const float* cb2 = (const float*)d_in[18];
  const float* cW3 = (const float*)d_in[19];
  const float* cb3 = (const float*)d_in[20];
  float* out = (float*)d_out;

  char* p = (char*)d_ws;
  auto alloc = [&](size_t bytes) {
    char* r = p;
    p += (bytes + 255) & ~(size_t)255;
    return r;
  };
  int* cnt = (int*)alloc((size_t)NN * 4);
  int* rs = (int*)alloc((size_t)(NN + 1) * 4);
  int* cur = (int*)alloc((size_t)NN * 4);
  int* ci = (int*)alloc((size_t)EE * 4);
  int* part = (int*)alloc(128 * 4);
  int* partx = (int*)alloc(128 * 4);
  unsigned short* h0 = (unsigned short*)alloc((size_t)NN * DD * 2);
  unsigned short* h1 = (unsigned short*)alloc((size_t)NN * 2 * DD * 2);
  unsigned short* xp = (unsigned short*)alloc((size_t)NN * DD * 2);
  float* stats = (float*)alloc(512 * 4);  // colsum[256] + colsq[256]
  float* colsum = stats;
  float* colsq = stats + 256;
  float* tsc1 = (float*)alloc(256 * 4);
  float* tsh1 = (float*)alloc(256 * 4);
  float* tscX = (float*)alloc(128 * 4);
  float* tshX = (float*)alloc(128 * 4);
  float* zbuf = (float*)alloc((size_t)GG * 384 * 4);
  float* z1 = (float*)alloc((size_t)GG * 128 * 4);
  unsigned short* W1t = (unsigned short*)alloc((size_t)4 * 256 * 128 * 2);
  unsigned short* W2t = (unsigned short*)alloc((size_t)4 * 128 * 256 * 2);
  (void)ws_size; (void)n_in; (void)in_sizes; (void)out_size;

  // weight convert+transpose to bf16 (static across layers/calls)
  k_conv<<<512, 256, 0, stream>>>(W1, W2, W1t, W2t);

  // CSR build (edges static across layers)
  hipMemsetAsync(cnt, 0, (size_t)NN * 4, stream);
  k_hist<<<(EE + 255) / 256, 256, 0, stream>>>(ei, cnt);
  const int nscan = (NN + 1023) / 1024;  // 98
  k_part<<<nscan, 1024, 0, stream>>>(cnt, part);
  k_scanpart<<<1, 128, 0, stream>>>(part, partx, nscan);
  k_rs<<<nscan, 1024, 0, stream>>>(cnt, partx, rs, cur);
  k_fill<<<(EE + 255) / 256, 256, 0, stream>>>(ei, cur, ci);

  const int gxg = (NN + 127) / 128;  // 782
  for (int l = 0; l < LL; ++l) {
    if (l == 0) {
      k_agg_f32<<<(NN * 32 + 255) / 256, 256, 0, stream>>>(x, rs, ci, epsv, h0, NN);
    } else {
      k_agg_bf16<<<(NN * 16 + 255) / 256, 256, 0, stream>>>(xp, rs, ci, epsv, l,
                                                            tscX, tshX, h0, NN);
    }
    hipMemsetAsync(stats, 0, 512 * 4, stream);
    k_gemm<128, 256><<<gxg, 512, 0, stream>>>(
        h0, 0, nullptr, nullptr, W1t + (size_t)l * 256 * 128,
        b1 + (size_t)l * 256, h1, colsum, colsq, NN);
    k_fin<<<1, 256, 0, stream>>>(colsum, colsq, g1 + (size_t)l * 256,
                                 be1 + (size_t)l * 256, tsc1, tsh1, 256, 1.0f / NN);
    hipMemsetAsync(stats, 0, 512 * 4, stream);
    k_gemm<256, 128><<<gxg, 512, 0, stream>>>(
        h1, 1, tsc1, tsh1, W2t + (size_t)l * 128 * 256,
        b2 + (size_t)l * 128, xp, colsum, colsq, NN);
    k_fin<<<1, 256, 0, stream>>>(colsum, colsq, gbn + (size_t)l * 128,
                                 bbn + (size_t)l * 128, tscX, tshX, 128, 1.0f / NN);
  }

  k_pool<<<GG, 128, 0, stream>>>(xp, batch, tscX, tshX, zbuf, NN);
  hipMemsetAsync(stats, 0, 512 * 4, stream);
  k_cls1<<<GG, 128, 0, stream>>>(zbuf, cW1, cb1, z1, colsum, colsq);
  k_fin<<<1, 256, 0, stream>>>(colsum, colsq, cg, cbeta, tscX, tshX, 128, 1.0f / GG);
  k_cls2<<<GG, 128, 0, stream>>>(z1, tscX, tshX, cW2, cb2, cW3, cb3, out);
}

// Round 8
// 870.711 us; speedup vs baseline: 2.1857x; 1.2014x over previous
//
#include <hip/hip_runtime.h>
#include <cstdint>
#include <cstddef>

// Problem constants (fixed by the reference setup_inputs).
#define NN 100000
#define EE 500000
#define DD 128
#define GG 512
#define LL 4
#define BN_EPS 1e-5f

typedef __attribute__((ext_vector_type(8))) short short8;
typedef __attribute__((ext_vector_type(8))) unsigned short ushort8v;
typedef __attribute__((ext_vector_type(4))) float f32x4;

static __device__ __forceinline__ unsigned short f2bf(float f) {
  union { float f; unsigned u; } v;
  v.f = f;
  unsigned r = v.u + 0x7fffu + ((v.u >> 16) & 1u);  // RNE
  return (unsigned short)(r >> 16);
}
static __device__ __forceinline__ float bf2f(unsigned short u) {
  union { unsigned u; float f; } v;
  v.u = ((unsigned)u) << 16;
  return v.f;
}

// ---------------- CSR build (int32 inputs) ----------------

__global__ void k_hist(const int* __restrict__ ei, int* __restrict__ cnt) {
  int e = blockIdx.x * 256 + threadIdx.x;
  if (e < EE) {
    int d = ei[EE + e];
    if (d >= 0 && d < NN) atomicAdd(&cnt[d], 1);
  }
}

__global__ void k_part(const int* __restrict__ cnt, int* __restrict__ part) {
  __shared__ int sm[1024];
  int t = threadIdx.x;
  int i = blockIdx.x * 1024 + t;
  sm[t] = (i < NN) ? cnt[i] : 0;
  __syncthreads();
  for (int off = 512; off > 0; off >>= 1) {
    if (t < off) sm[t] += sm[t + off];
    __syncthreads();
  }
  if (t == 0) part[blockIdx.x] = sm[0];
}

__global__ void k_scanpart(const int* __restrict__ part, int* __restrict__ partx, int nb) {
  __shared__ int sm[128];
  int t = threadIdx.x;
  int v = (t < nb) ? part[t] : 0;
  sm[t] = v;
  __syncthreads();
  for (int off = 1; off < 128; off <<= 1) {
    int u = (t >= off) ? sm[t - off] : 0;
    __syncthreads();
    sm[t] += u;
    __syncthreads();
  }
  if (t < nb) partx[t] = sm[t] - v;
}

__global__ void k_rs(const int* __restrict__ cnt, const int* __restrict__ partx,
                     int* __restrict__ rs, int* __restrict__ cur) {
  __shared__ int sm[1024];
  int t = threadIdx.x;
  int i = blockIdx.x * 1024 + t;
  int v = (i < NN) ? cnt[i] : 0;
  sm[t] = v;
  __syncthreads();
  for (int off = 1; off < 1024; off <<= 1) {
    int u = (t >= off) ? sm[t - off] : 0;
    __syncthreads();
    sm[t] += u;
    __syncthreads();
  }
  if (i < NN) {
    int excl = partx[blockIdx.x] + sm[t] - v;
    rs[i] = excl;
    cur[i] = excl;
    if (i == NN - 1) rs[NN] = excl + v;
  }
}

__global__ void k_fill(const int* __restrict__ ei, int* __restrict__ cur,
                       int* __restrict__ ci) {
  int e = blockIdx.x * 256 + threadIdx.x;
  if (e < EE) {
    int s = ei[e];
    int d = ei[EE + e];
    if (d >= 0 && d < NN && s >= 0 && s < NN) {
      int pos = atomicAdd(&cur[d], 1);
      if (pos >= 0 && pos < EE) ci[pos] = s;  // order irrelevant (sum)
    }
  }
}

// ---------------- weight convert: W -> W^T in bf16, once per call ----------------

__global__ void k_conv(const float* __restrict__ W1, const float* __restrict__ W2,
                       unsigned short* __restrict__ W1t, unsigned short* __restrict__ W2t) {
  int idx = blockIdx.x * 256 + threadIdx.x;
  if (idx < 4 * 256 * 128) {
    {  // W1: [l][k][nc] (K=128,NC=256) -> [l][nc][k]
      int l = idx >> 15, rem = idx & 32767;
      int nc = rem >> 7, k = rem & 127;
      W1t[idx] = f2bf(W1[(l << 15) + k * 256 + nc]);
    }
    {  // W2: [l][k][nc] (K=256,NC=128) -> [l][nc][k]
      int l = idx >> 15, rem = idx & 32767;
      int nc = rem >> 8, k = rem & 255;
      W2t[idx] = f2bf(W2[(l << 15) + k * 128 + nc]);
    }
  }
}

// ---------------- aggregation (layer 0): fp32 x in, bf16 h0 out ----------------
// 32 lanes/node, float4.

__global__ __launch_bounds__(256) void k_agg_f32(
    const float* __restrict__ X, const int* __restrict__ rs,
    const int* __restrict__ ci, const float* __restrict__ epsv,
    unsigned short* __restrict__ h0, int n) {
  int idx = blockIdx.x * 256 + threadIdx.x;
  int node = idx >> 5;
  int c4 = (idx & 31) << 2;
  if (node >= n) return;
  float4 v = *(const float4*)(X + (size_t)node * DD + c4);
  float se = 1.f + epsv[0];
  float4 acc;
  acc.x = se * v.x; acc.y = se * v.y; acc.z = se * v.z; acc.w = se * v.w;
  int e0 = rs[node], e1 = rs[node + 1];
  for (int j = e0; j < e1; ++j) {
    int nb = ci[j];
    float4 u = *(const float4*)(X + (size_t)nb * DD + c4);
    acc.x += u.x; acc.y += u.y; acc.z += u.z; acc.w += u.w;
  }
  ushort4 o;
  o.x = f2bf(acc.x); o.y = f2bf(acc.y); o.z = f2bf(acc.z); o.w = f2bf(acc.w);
  *(ushort4*)(h0 + (size_t)node * DD + c4) = o;
}

// ---------------- aggregation (layers 1+): bf16 X in (+BN/ReLU), bf16 h0 out ----
// 16 lanes/node, ushort8 (16B) loads, 1-deep neighbor prefetch.

__global__ __launch_bounds__(256) void k_agg_bf16(
    const unsigned short* __restrict__ X, const int* __restrict__ rs,
    const int* __restrict__ ci, const float* __restrict__ epsv, int l,
    const float* __restrict__ tsc, const float* __restrict__ tsh,
    unsigned short* __restrict__ h0, int n) {
  int idx = blockIdx.x * 256 + threadIdx.x;
  int node = idx >> 4;
  int c8 = (idx & 15) << 3;
  if (node >= n) return;
  float4 a0 = *(const float4*)(tsc + c8), a1 = *(const float4*)(tsc + c8 + 4);
  float4 b0 = *(const float4*)(tsh + c8), b1 = *(const float4*)(tsh + c8 + 4);
  float sa[8] = {a0.x, a0.y, a0.z, a0.w, a1.x, a1.y, a1.z, a1.w};
  float sb[8] = {b0.x, b0.y, b0.z, b0.w, b1.x, b1.y, b1.z, b1.w};
  float se = 1.f + epsv[l];
  ushort8v v = *(const ushort8v*)(X + (size_t)node * DD + c8);
  float acc[8];
#pragma unroll
  for (int j = 0; j < 8; ++j)
    acc[j] = se * fmaxf(0.f, bf2f(v[j]) * sa[j] + sb[j]);
  int e0 = rs[node], e1 = rs[node + 1];
  ushort8v un;
  if (e0 < e1) un = *(const ushort8v*)(X + (size_t)ci[e0] * DD + c8);
  for (int e = e0; e < e1; ++e) {
    ushort8v uc = un;
    if (e + 1 < e1) un = *(const ushort8v*)(X + (size_t)ci[e + 1] * DD + c8);
#pragma unroll
    for (int j = 0; j < 8; ++j)
      acc[j] += fmaxf(0.f, bf2f(uc[j]) * sa[j] + sb[j]);
  }
  ushort8v o;
#pragma unroll
  for (int j = 0; j < 8; ++j) o[j] = f2bf(acc[j]);
  *(ushort8v*)(h0 + (size_t)node * DD + c8) = o;
}

// ---------------- MFMA bf16 GEMM: bf16 A (opt. BN/ReLU on read), bf16 C out ------
// GM=128 rows/block, 512 threads = 8 waves x 16 rows. BK=64 chunks, col-groups of
// 128 (8 frags/wave). NO global atomics: per-block column (sum,sumsq) partials to
// psum/psq (coalesced), reduced by k_finred. C staged through LDS for coalesced
// ushort8 stores. LDS ~38KB -> 3 blocks/CU.

template <int K, int NC>
__global__ __launch_bounds__(512) void k_gemm(
    const unsigned short* __restrict__ A, int mode, const float* __restrict__ tsc,
    const float* __restrict__ tsh, const unsigned short* __restrict__ Bt,
    const float* __restrict__ bias, unsigned short* __restrict__ C,
    float* __restrict__ psum, float* __restrict__ psq, int n) {
  constexpr int KC = 64;        // k-chunk
  constexpr int KT = K / KC;    // chunks (2 or 4)
  constexpr int NT = NC / 128;  // col-groups (2 or 1)
  constexpr int AST = 72;       // stage row stride (ushorts), 144B
  constexpr int CTP = 136;      // C-tile row stride (ushorts), 272B
  __shared__ __align__(16) unsigned short smem[2 * 128 * AST];  // 36864 B
  __shared__ float bsum[128], bsq[128];
  unsigned short* Asm = smem;              // [128][AST]
  unsigned short* Bsm = smem + 128 * AST;  // [128][AST]
  unsigned short* Ct = smem;               // epilogue reuse: [128][CTP] (17408 <= 18432)

  int tid = threadIdx.x;
  int lane = tid & 63, wave = tid >> 6;
  int quad = lane >> 4, l15 = lane & 15;
  int row0 = blockIdx.x * 128;
  int blk = blockIdx.x;

  for (int cg = 0; cg < NT; ++cg) {
    f32x4 acc[8];
#pragma unroll
    for (int j = 0; j < 8; ++j) acc[j] = (f32x4){0.f, 0.f, 0.f, 0.f};

    for (int kc = 0; kc < KT; ++kc) {
      __syncthreads();  // smem free (prior mfma / prior epilogue Ct reads done)
      // stage A chunk: 128 rows x 64 k (1024 ushort8, 2/thread)
#pragma unroll
      for (int it = 0; it < 2; ++it) {
        int f = tid + it * 512;
        int r = f >> 3;
        int c8 = (f & 7) << 3;
        int gr = row0 + r;
        ushort8v v = (ushort8v){0, 0, 0, 0, 0, 0, 0, 0};
        if (gr < n) v = *(const ushort8v*)(A + (size_t)gr * K + kc * KC + c8);
        if (mode) {
          int kg = kc * KC + c8;
          float4 s0 = *(const float4*)(tsc + kg);
          float4 s1 = *(const float4*)(tsc + kg + 4);
          float4 t0 = *(const float4*)(tsh + kg);
          float4 t1 = *(const float4*)(tsh + kg + 4);
          float sa[8] = {s0.x, s0.y, s0.z, s0.w, s1.x, s1.y, s1.z, s1.w};
          float sb[8] = {t0.x, t0.y, t0.z, t0.w, t1.x, t1.y, t1.z, t1.w};
#pragma unroll
          for (int j = 0; j < 8; ++j)
            v[j] = f2bf(fmaxf(0.f, bf2f(v[j]) * sa[j] + sb[j]));
        }
        *(ushort8v*)(&Asm[r * AST + c8]) = v;
      }
      // stage B chunk: 128 cols x 64 k
#pragma unroll
      for (int it = 0; it < 2; ++it) {
        int f = tid + it * 512;
        int r = f >> 3;
        int c8 = (f & 7) << 3;
        *(ushort8v*)(&Bsm[r * AST + c8]) =
            *(const ushort8v*)(Bt + (size_t)(cg * 128 + r) * K + kc * KC + c8);
      }
      __syncthreads();
#pragma unroll
      for (int kk = 0; kk < KC; kk += 32) {
        int ko = kk + quad * 8;
        short8 av = *(const short8*)(&Asm[(wave * 16 + l15) * AST + ko]);
#pragma unroll
        for (int cf = 0; cf < 8; ++cf) {
          short8 bv = *(const short8*)(&Bsm[(cf * 16 + l15) * AST + ko]);
          acc[cf] = __builtin_amdgcn_mfma_f32_16x16x32_bf16(av, bv, acc[cf], 0, 0, 0);
        }
      }
    }

    // ---- epilogue ----
    __syncthreads();  // all mfma LDS reads done; smem reusable as Ct
    if (tid < 128) { bsum[tid] = 0.f; bsq[tid] = 0.f; }
    float s8[8], q8[8];
#pragma unroll
    for (int j = 0; j < 8; ++j) { s8[j] = 0.f; q8[j] = 0.f; }
    int lrbase = wave * 16 + quad * 4;  // local row base
#pragma unroll
    for (int cf = 0; cf < 8; ++cf) {
      int col = cg * 128 + cf * 16 + l15;
      float bv = bias[col];
#pragma unroll
      for (int reg = 0; reg < 4; ++reg) {
        int lr = lrbase + reg;
        float e = acc[cf][reg] + bv;
        Ct[lr * CTP + cf * 16 + l15] = f2bf(e);
        if (row0 + lr < n) { s8[cf] += e; q8[cf] += e * e; }
      }
    }
#pragma unroll
    for (int cf = 0; cf < 8; ++cf) {
      s8[cf] += __shfl_xor(s8[cf], 16, 64);
      s8[cf] += __shfl_xor(s8[cf], 32, 64);
      q8[cf] += __shfl_xor(q8[cf], 16, 64);
      q8[cf] += __shfl_xor(q8[cf], 32, 64);
    }
    __syncthreads();  // Ct complete; bsum zeroed
    if (quad == 0) {
#pragma unroll
      for (int cf = 0; cf < 8; ++cf) {
        atomicAdd(&bsum[cf * 16 + l15], s8[cf]);
        atomicAdd(&bsq[cf * 16 + l15], q8[cf]);
      }
    }
    // coalesced C store: 16B/lane
#pragma unroll
    for (int it = 0; it < 4; ++it) {
      int f = tid + it * 512;
      int r = f >> 4;
      int c8 = (f & 15) << 3;
      int gr = row0 + r;
      if (gr < n)
        *(ushort8v*)(C + (size_t)gr * NC + cg * 128 + c8) =
            *(const ushort8v*)(&Ct[r * CTP + c8]);
    }
    __syncthreads();  // bsum atomics done
    if (tid < 128) {
      psum[(size_t)blk * NC + cg * 128 + tid] = bsum[tid];
      psq[(size_t)blk * NC + cg * 128 + tid] = bsq[tid];
    }
  }
}

// ---------------- column-stat reduce + BN finalize (one block per column) --------

__global__ __launch_bounds__(256) void k_finred(
    const float* __restrict__ psum, const float* __restrict__ psq, int nb, int nc,
    const float* __restrict__ g, const float* __restrict__ be,
    float* __restrict__ osc, float* __restrict__ osh, float invn) {
  __shared__ float ws[4], wq[4];
  int col = blockIdx.x;
  int t = threadIdx.x;
  float s = 0.f, q = 0.f;
  for (int b = t; b < nb; b += 256) {
    s += psum[(size_t)b * nc + col];
    q += psq[(size_t)b * nc + col];
  }
#pragma unroll
  for (int off = 32; off > 0; off >>= 1) {
    s += __shfl_xor(s, off, 64);
    q += __shfl_xor(q, off, 64);
  }
  if ((t & 63) == 0) { ws[t >> 6] = s; wq[t >> 6] = q; }
  __syncthreads();
  if (t == 0) {
    s = ws[0] + ws[1] + ws[2] + ws[3];
    q = wq[0] + wq[1] + wq[2] + wq[3];
    float m = s * invn;
    float v = fmaxf(q * invn - m * m, 0.f);
    float sc = g[col] * rsqrtf(v + BN_EPS);
    osc[col] = sc;
    osh[col] = be[col] - m * sc;
  }
}

// ---------------- BN stat finalize (classifier path) ----------------

__global__ void k_fin(const float* __restrict__ colsum, const float* __restrict__ colsq,
                      const float* __restrict__ g, const float* __restrict__ be,
                      float* __restrict__ osc, float* __restrict__ osh, int nc,
                      float invn) {
  int c = threadIdx.x;
  if (c < nc) {
    float m = colsum[c] * invn;
    float v = fmaxf(colsq[c] * invn - m * m, 0.f);
    float sc = g[c] * rsqrtf(v + BN_EPS);
    osc[c] = sc;
    osh[c] = be[c] - m * sc;
  }
}

// ---------------- pooling (batch sorted -> contiguous ranges), bf16 X ------------

static __device__ __forceinline__ int lb_i32(const int* a, int n, int key) {
  int lo = 0, hi = n;
  while (lo < hi) {
    int mid = (lo + hi) >> 1;
    if (a[mid] < key) lo = mid + 1; else hi = mid;
  }
  return lo;
}

__global__ void k_pool(const unsigned short* __restrict__ X, const int* __restrict__ batch,
                       const float* __restrict__ tsc, const float* __restrict__ tsh,
                       float* __restrict__ z, int n) {
  int g = blockIdx.x;
  int c = threadIdx.x;  // 128
  __shared__ int slo, shi;
  if (c == 0) {
    slo = lb_i32(batch, n, g);
    shi = lb_i32(batch, n, g + 1);
  }
  __syncthreads();
  int lo = slo, hi = shi;
  float a = tsc[c], b = tsh[c];
  float s = 0.f, m = -3.402823466e38f;
  for (int i = lo; i < hi; ++i) {
    float v = fmaxf(0.f, bf2f(X[(size_t)i * DD + c]) * a + b);
    s += v;
    m = fmaxf(m, v);
  }
  float cntf = (float)(hi - lo);
  z[(size_t)g * 384 + c] = s;
  z[(size_t)g * 384 + 128 + c] = s / fmaxf(cntf, 1.f);
  z[(size_t)g * 384 + 256 + c] = m;
}

// ---------------- classifier head (fp32, tiny) ----------------

__global__ void k_cls1(const float* __restrict__ z, const float* __restrict__ cW1,
                       const float* __restrict__ cb1, float* __restrict__ z1,
                       float* __restrict__ colsum, float* __restrict__ colsq) {
  __shared__ float zr[384];
  int g = blockIdx.x;
  int c = threadIdx.x;  // 128
  for (int i = c; i < 384; i += 128) zr[i] = z[(size_t)g * 384 + i];
  __syncthreads();
  float s = cb1[c];
#pragma unroll 4
  for (int k = 0; k < 384; ++k) s = fmaf(zr[k], cW1[(size_t)k * 128 + c], s);
  z1[(size_t)g * 128 + c] = s;
  atomicAdd(&colsum[c], s);
  atomicAdd(&colsq[c], s * s);
}

__global__ void k_cls2(const float* __restrict__ z1, const float* __restrict__ csc,
                       const float* __restrict__ csh, const float* __restrict__ cW2,
                       const float* __restrict__ cb2, const float* __restrict__ cW3,
                       const float* __restrict__ cb3, float* __restrict__ out) {
  __shared__ float z1n[128];
  __shared__ float z2s[64];
  int g = blockIdx.x;
  int t = threadIdx.x;  // 128
  z1n[t] = fmaxf(0.f, z1[(size_t)g * 128 + t] * csc[t] + csh[t]);
  __syncthreads();
  if (t < 64) {
    float s = cb2[t];
#pragma unroll 4
    for (int k = 0; k < 128; ++k) s = fmaf(z1n[k], cW2[(size_t)k * 64 + t], s);
    z2s[t] = fmaxf(0.f, s);
  }
  __syncthreads();
  if (t < 2) {
    float s = cb3[t];
#pragma unroll 4
    for (int c = 0; c < 64; ++c) s = fmaf(z2s[c], cW3[(size_t)c * 2 + t], s);
    out[(size_t)g * 2 + t] = s;
  }
}

// ---------------- launch ----------------

extern "C" void kernel_launch(void* const* d_in, const int* in_sizes, int n_in,
                              void* d_out, int out_size, void* d_ws, size_t ws_size,
                              hipStream_t stream) {
  const float* x = (const float*)d_in[0];
  const int* ei = (const int*)d_in[1];     // int32 (harness downcasts int64)
  const int* batch = (const int*)d_in[2];  // int32
  const float* W1 = (const float*)d_in[4];
  const float* b1 = (const float*)d_in[5];
  const float* g1 = (const float*)d_in[6];
  const float* be1 = (const float*)d_in[7];
  const float* W2 = (const float*)d_in[8];
  const float* b2 = (const float*)d_in[9];
  const float* gbn = (const float*)d_in[10];
  const float* bbn = (const float*)d_in[11];
  const float* epsv = (const float*)d_in[12];
  const float* cW1 = (const float*)d_in[13];
  const float* cb1 = (const float*)d_in[14];
  const float* cg = (const float*)d_in[15];
  const float* cbeta = (const float*)d_in[16];
  const float* cW2 = (const float*)d_in[17];
  const float* cb2 = (const float*)d_in[18];
  const float* cW3 = (const float*)d_in[19];
  const float* cb3 = (const float*)d_in[20];
  float* out = (float*)d_out;

  char* p = (char*)d_ws;
  auto alloc = [&](size_t bytes) {
    char* r = p;
    p += (bytes + 255) & ~(size_t)255;
    return r;
  };
  const int NB = (NN + 127) / 128;  // 782 GEMM row-blocks
  int* cnt = (int*)alloc((size_t)NN * 4);
  int* rs = (int*)alloc((size_t)(NN + 1) * 4);
  int* cur = (int*)alloc((size_t)NN * 4);
  int* ci = (int*)alloc((size_t)EE * 4);
  int* part = (int*)alloc(128 * 4);
  int* partx = (int*)alloc(128 * 4);
  unsigned short* h0 = (unsigned short*)alloc((size_t)NN * DD * 2);
  unsigned short* h1 = (unsigned short*)alloc((size_t)NN * 2 * DD * 2);
  unsigned short* xp = (unsigned short*)alloc((size_t)NN * DD * 2);
  float* psum = (float*)alloc((size_t)NB * 256 * 4);
  float* psq = (float*)alloc((size_t)NB * 256 * 4);
  float* stats = (float*)alloc(512 * 4);  // cls colsum[256] + colsq[256]
  float* colsum = stats;
  float* colsq = stats + 256;
  float* tsc1 = (float*)alloc(256 * 4);
  float* tsh1 = (float*)alloc(256 * 4);
  float* tscX = (float*)alloc(128 * 4);
  float* tshX = (float*)alloc(128 * 4);
  float* zbuf = (float*)alloc((size_t)GG * 384 * 4);
  float* z1 = (float*)alloc((size_t)GG * 128 * 4);
  unsigned short* W1t = (unsigned short*)alloc((size_t)4 * 256 * 128 * 2);
  unsigned short* W2t = (unsigned short*)alloc((size_t)4 * 128 * 256 * 2);
  (void)ws_size; (void)n_in; (void)in_sizes; (void)out_size;

  // weight convert+transpose to bf16 (static across layers/calls)
  k_conv<<<512, 256, 0, stream>>>(W1, W2, W1t, W2t);

  // CSR build (edges static across layers)
  hipMemsetAsync(cnt, 0, (size_t)NN * 4, stream);
  k_hist<<<(EE + 255) / 256, 256, 0, stream>>>(ei, cnt);
  const int nscan = (NN + 1023) / 1024;  // 98
  k_part<<<nscan, 1024, 0, stream>>>(cnt, part);
  k_scanpart<<<1, 128, 0, stream>>>(part, partx, nscan);
  k_rs<<<nscan, 1024, 0, stream>>>(cnt, partx, rs, cur);
  k_fill<<<(EE + 255) / 256, 256, 0, stream>>>(ei, cur, ci);

  for (int l = 0; l < LL; ++l) {
    if (l == 0) {
      k_agg_f32<<<(NN * 32 + 255) / 256, 256, 0, stream>>>(x, rs, ci, epsv, h0, NN);
    } else {
      k_agg_bf16<<<(NN * 16 + 255) / 256, 256, 0, stream>>>(xp, rs, ci, epsv, l,
                                                            tscX, tshX, h0, NN);
    }
    k_gemm<128, 256><<<NB, 512, 0, stream>>>(
        h0, 0, nullptr, nullptr, W1t + (size_t)l * 256 * 128,
        b1 + (size_t)l * 256, h1, psum, psq, NN);
    k_finred<<<256, 256, 0, stream>>>(psum, psq, NB, 256, g1 + (size_t)l * 256,
                                      be1 + (size_t)l * 256, tsc1, tsh1, 1.0f / NN);
    k_gemm<256, 128><<<NB, 512, 0, stream>>>(
        h1, 1, tsc1, tsh1, W2t + (size_t)l * 128 * 256,
        b2 + (size_t)l * 128, xp, psum, psq, NN);
    k_finred<<<128, 256, 0, stream>>>(psum, psq, NB, 128, gbn + (size_t)l * 128,
                                      bbn + (size_t)l * 128, tscX, tshX, 1.0f / NN);
  }

  k_pool<<<GG, 128, 0, stream>>>(xp, batch, tscX, tshX, zbuf, NN);
  hipMemsetAsync(stats, 0, 512 * 4, stream);
  k_cls1<<<GG, 128, 0, stream>>>(zbuf, cW1, cb1, z1, colsum, colsq);
  k_fin<<<1, 256, 0, stream>>>(colsum, colsq, cg, cbeta, tscX, tshX, 128, 1.0f / GG);
  k_cls2<<<GG, 128, 0, stream>>>(z1, tscX, tshX, cW2, cb2, cW3, cb3, out);
}

// Round 9
// 809.688 us; speedup vs baseline: 2.3504x; 1.0754x over previous
//
#include <hip/hip_runtime.h>
#include <cstdint>
#include <cstddef>

// Problem constants (fixed by the reference setup_inputs).
#define NN 100000
#define EE 500000
#define DD 128
#define GG 512
#define LL 4
#define BN_EPS 1e-5f

typedef __attribute__((ext_vector_type(8))) short short8;
typedef __attribute__((ext_vector_type(8))) unsigned short ushort8v;
typedef __attribute__((ext_vector_type(4))) float f32x4;

static __device__ __forceinline__ unsigned short f2bf(float f) {
  union { float f; unsigned u; } v;
  v.f = f;
  unsigned r = v.u + 0x7fffu + ((v.u >> 16) & 1u);  // RNE
  return (unsigned short)(r >> 16);
}
static __device__ __forceinline__ float bf2f(unsigned short u) {
  union { unsigned u; float f; } v;
  v.u = ((unsigned)u) << 16;
  return v.f;
}

// ---------------- CSR build (int32 inputs) ----------------

__global__ void k_hist(const int* __restrict__ ei, int* __restrict__ cnt) {
  int e = blockIdx.x * 256 + threadIdx.x;
  if (e < EE) {
    int d = ei[EE + e];
    if (d >= 0 && d < NN) atomicAdd(&cnt[d], 1);
  }
}

__global__ void k_part(const int* __restrict__ cnt, int* __restrict__ part) {
  __shared__ int sm[1024];
  int t = threadIdx.x;
  int i = blockIdx.x * 1024 + t;
  sm[t] = (i < NN) ? cnt[i] : 0;
  __syncthreads();
  for (int off = 512; off > 0; off >>= 1) {
    if (t < off) sm[t] += sm[t + off];
    __syncthreads();
  }
  if (t == 0) part[blockIdx.x] = sm[0];
}

__global__ void k_scanpart(const int* __restrict__ part, int* __restrict__ partx, int nb) {
  __shared__ int sm[128];
  int t = threadIdx.x;
  int v = (t < nb) ? part[t] : 0;
  sm[t] = v;
  __syncthreads();
  for (int off = 1; off < 128; off <<= 1) {
    int u = (t >= off) ? sm[t - off] : 0;
    __syncthreads();
    sm[t] += u;
    __syncthreads();
  }
  if (t < nb) partx[t] = sm[t] - v;
}

__global__ void k_rs(const int* __restrict__ cnt, const int* __restrict__ partx,
                     int* __restrict__ rs, int* __restrict__ cur) {
  __shared__ int sm[1024];
  int t = threadIdx.x;
  int i = blockIdx.x * 1024 + t;
  int v = (i < NN) ? cnt[i] : 0;
  sm[t] = v;
  __syncthreads();
  for (int off = 1; off < 1024; off <<= 1) {
    int u = (t >= off) ? sm[t - off] : 0;
    __syncthreads();
    sm[t] += u;
    __syncthreads();
  }
  if (i < NN) {
    int excl = partx[blockIdx.x] + sm[t] - v;
    rs[i] = excl;
    cur[i] = excl;
    if (i == NN - 1) rs[NN] = excl + v;
  }
}

__global__ void k_fill(const int* __restrict__ ei, int* __restrict__ cur,
                       int* __restrict__ ci) {
  int e = blockIdx.x * 256 + threadIdx.x;
  if (e < EE) {
    int s = ei[e];
    int d = ei[EE + e];
    if (d >= 0 && d < NN && s >= 0 && s < NN) {
      int pos = atomicAdd(&cur[d], 1);
      if (pos >= 0 && pos < EE) ci[pos] = s;  // order irrelevant (sum)
    }
  }
}

// ---------------- weight convert: W -> W^T in bf16, once per call ----------------

__global__ void k_conv(const float* __restrict__ W1, const float* __restrict__ W2,
                       unsigned short* __restrict__ W1t, unsigned short* __restrict__ W2t) {
  int idx = blockIdx.x * 256 + threadIdx.x;
  if (idx < 4 * 256 * 128) {
    {  // W1: [l][k][nc] (K=128,NC=256) -> [l][nc][k]
      int l = idx >> 15, rem = idx & 32767;
      int nc = rem >> 7, k = rem & 127;
      W1t[idx] = f2bf(W1[(l << 15) + k * 256 + nc]);
    }
    {  // W2: [l][k][nc] (K=256,NC=128) -> [l][nc][k]
      int l = idx >> 15, rem = idx & 32767;
      int nc = rem >> 8, k = rem & 255;
      W2t[idx] = f2bf(W2[(l << 15) + k * 128 + nc]);
    }
  }
}

// ---------------- x -> bf16 convert (streaming, once per call) ----------------

__global__ void k_x2bf(const float* __restrict__ x, unsigned short* __restrict__ xb) {
  int i = blockIdx.x * 256 + threadIdx.x;
  if (i < NN * DD / 4) {
    float4 v = *(const float4*)(x + (size_t)i * 4);
    ushort4 o;
    o.x = f2bf(v.x); o.y = f2bf(v.y); o.z = f2bf(v.z); o.w = f2bf(v.w);
    *(ushort4*)(xb + (size_t)i * 4) = o;
  }
}

// ---------------- aggregation: bf16 X in (opt. BN/ReLU), bf16 h0 out ----
// 16 lanes/node, ushort8 (16B) loads, 1-deep neighbor prefetch.
// mode=0: raw sum (layer 0). mode=1: relu(tsc*x+tsh) per element on read.

__global__ __launch_bounds__(256) void k_agg_bf16(
    const unsigned short* __restrict__ X, const int* __restrict__ rs,
    const int* __restrict__ ci, const float* __restrict__ epsv, int l, int mode,
    const float* __restrict__ tsc, const float* __restrict__ tsh,
    unsigned short* __restrict__ h0, int n) {
  int idx = blockIdx.x * 256 + threadIdx.x;
  int node = idx >> 4;
  int c8 = (idx & 15) << 3;
  if (node >= n) return;
  float sa[8], sb[8];
  if (mode) {
    float4 a0 = *(const float4*)(tsc + c8), a1 = *(const float4*)(tsc + c8 + 4);
    float4 b0 = *(const float4*)(tsh + c8), b1 = *(const float4*)(tsh + c8 + 4);
    sa[0] = a0.x; sa[1] = a0.y; sa[2] = a0.z; sa[3] = a0.w;
    sa[4] = a1.x; sa[5] = a1.y; sa[6] = a1.z; sa[7] = a1.w;
    sb[0] = b0.x; sb[1] = b0.y; sb[2] = b0.z; sb[3] = b0.w;
    sb[4] = b1.x; sb[5] = b1.y; sb[6] = b1.z; sb[7] = b1.w;
  }
  float se = 1.f + epsv[l];
  ushort8v v = *(const ushort8v*)(X + (size_t)node * DD + c8);
  float acc[8];
#pragma unroll
  for (int j = 0; j < 8; ++j) {
    float f = bf2f(v[j]);
    if (mode) f = fmaxf(0.f, f * sa[j] + sb[j]);
    acc[j] = se * f;
  }
  int e0 = rs[node], e1 = rs[node + 1];
  ushort8v un;
  if (e0 < e1) un = *(const ushort8v*)(X + (size_t)ci[e0] * DD + c8);
  for (int e = e0; e < e1; ++e) {
    ushort8v uc = un;
    if (e + 1 < e1) un = *(const ushort8v*)(X + (size_t)ci[e + 1] * DD + c8);
#pragma unroll
    for (int j = 0; j < 8; ++j) {
      float f = bf2f(uc[j]);
      if (mode) f = fmaxf(0.f, f * sa[j] + sb[j]);
      acc[j] += f;
    }
  }
  ushort8v o;
#pragma unroll
  for (int j = 0; j < 8; ++j) o[j] = f2bf(acc[j]);
  *(ushort8v*)(h0 + (size_t)node * DD + c8) = o;
}

// ---------------- MFMA bf16 GEMM: bf16 A (opt. BN/ReLU on read), bf16 C out ------
// GM=128 rows/block, 512 threads = 8 waves x 16 rows. BK=64 chunks, col-groups of
// 128 (8 frags/wave). NO global atomics: per-block column (sum,sumsq) partials to
// psum/psq (coalesced), reduced by k_finred. C staged through LDS for coalesced
// ushort8 stores. LDS ~38KB -> 3 blocks/CU.

template <int K, int NC>
__global__ __launch_bounds__(512) void k_gemm(
    const unsigned short* __restrict__ A, int mode, const float* __restrict__ tsc,
    const float* __restrict__ tsh, const unsigned short* __restrict__ Bt,
    const float* __restrict__ bias, unsigned short* __restrict__ C,
    float* __restrict__ psum, float* __restrict__ psq, int n) {
  constexpr int KC = 64;        // k-chunk
  constexpr int KT = K / KC;    // chunks (2 or 4)
  constexpr int NT = NC / 128;  // col-groups (2 or 1)
  constexpr int AST = 72;       // stage row stride (ushorts), 144B
  constexpr int CTP = 136;      // C-tile row stride (ushorts), 272B
  __shared__ __align__(16) unsigned short smem[2 * 128 * AST];  // 36864 B
  __shared__ float bsum[128], bsq[128];
  unsigned short* Asm = smem;              // [128][AST]
  unsigned short* Bsm = smem + 128 * AST;  // [128][AST]
  unsigned short* Ct = smem;               // epilogue reuse: [128][CTP]

  int tid = threadIdx.x;
  int lane = tid & 63, wave = tid >> 6;
  int quad = lane >> 4, l15 = lane & 15;
  int row0 = blockIdx.x * 128;
  int blk = blockIdx.x;

  for (int cg = 0; cg < NT; ++cg) {
    f32x4 acc[8];
#pragma unroll
    for (int j = 0; j < 8; ++j) acc[j] = (f32x4){0.f, 0.f, 0.f, 0.f};

    for (int kc = 0; kc < KT; ++kc) {
      __syncthreads();  // smem free (prior mfma / prior epilogue Ct reads done)
      // stage A chunk: 128 rows x 64 k (1024 ushort8, 2/thread)
#pragma unroll
      for (int it = 0; it < 2; ++it) {
        int f = tid + it * 512;
        int r = f >> 3;
        int c8 = (f & 7) << 3;
        int gr = row0 + r;
        ushort8v v = (ushort8v){0, 0, 0, 0, 0, 0, 0, 0};
        if (gr < n) v = *(const ushort8v*)(A + (size_t)gr * K + kc * KC + c8);
        if (mode) {
          int kg = kc * KC + c8;
          float4 s0 = *(const float4*)(tsc + kg);
          float4 s1 = *(const float4*)(tsc + kg + 4);
          float4 t0 = *(const float4*)(tsh + kg);
          float4 t1 = *(const float4*)(tsh + kg + 4);
          float sa[8] = {s0.x, s0.y, s0.z, s0.w, s1.x, s1.y, s1.z, s1.w};
          float sb[8] = {t0.x, t0.y, t0.z, t0.w, t1.x, t1.y, t1.z, t1.w};
#pragma unroll
          for (int j = 0; j < 8; ++j)
            v[j] = f2bf(fmaxf(0.f, bf2f(v[j]) * sa[j] + sb[j]));
        }
        *(ushort8v*)(&Asm[r * AST + c8]) = v;
      }
      // stage B chunk: 128 cols x 64 k
#pragma unroll
      for (int it = 0; it < 2; ++it) {
        int f = tid + it * 512;
        int r = f >> 3;
        int c8 = (f & 7) << 3;
        *(ushort8v*)(&Bsm[r * AST + c8]) =
            *(const ushort8v*)(Bt + (size_t)(cg * 128 + r) * K + kc * KC + c8);
      }
      __syncthreads();
#pragma unroll
      for (int kk = 0; kk < KC; kk += 32) {
        int ko = kk + quad * 8;
        short8 av = *(const short8*)(&Asm[(wave * 16 + l15) * AST + ko]);
#pragma unroll
        for (int cf = 0; cf < 8; ++cf) {
          short8 bv = *(const short8*)(&Bsm[(cf * 16 + l15) * AST + ko]);
          acc[cf] = __builtin_amdgcn_mfma_f32_16x16x32_bf16(av, bv, acc[cf], 0, 0, 0);
        }
      }
    }

    // ---- epilogue ----
    __syncthreads();  // all mfma LDS reads done; smem reusable as Ct
    if (tid < 128) { bsum[tid] = 0.f; bsq[tid] = 0.f; }
    float s8[8], q8[8];
#pragma unroll
    for (int j = 0; j < 8; ++j) { s8[j] = 0.f; q8[j] = 0.f; }
    int lrbase = wave * 16 + quad * 4;  // local row base
#pragma unroll
    for (int cf = 0; cf < 8; ++cf) {
      int col = cg * 128 + cf * 16 + l15;
      float bv = bias[col];
#pragma unroll
      for (int reg = 0; reg < 4; ++reg) {
        int lr = lrbase + reg;
        float e = acc[cf][reg] + bv;
        Ct[lr * CTP + cf * 16 + l15] = f2bf(e);
        if (row0 + lr < n) { s8[cf] += e; q8[cf] += e * e; }
      }
    }
#pragma unroll
    for (int cf = 0; cf < 8; ++cf) {
      s8[cf] += __shfl_xor(s8[cf], 16, 64);
      s8[cf] += __shfl_xor(s8[cf], 32, 64);
      q8[cf] += __shfl_xor(q8[cf], 16, 64);
      q8[cf] += __shfl_xor(q8[cf], 32, 64);
    }
    __syncthreads();  // Ct complete; bsum zeroed
    if (quad == 0) {
#pragma unroll
      for (int cf = 0; cf < 8; ++cf) {
        atomicAdd(&bsum[cf * 16 + l15], s8[cf]);
        atomicAdd(&bsq[cf * 16 + l15], q8[cf]);
      }
    }
    // coalesced C store: 16B/lane
#pragma unroll
    for (int it = 0; it < 4; ++it) {
      int f = tid + it * 512;
      int r = f >> 4;
      int c8 = (f & 15) << 3;
      int gr = row0 + r;
      if (gr < n)
        *(ushort8v*)(C + (size_t)gr * NC + cg * 128 + c8) =
            *(const ushort8v*)(&Ct[r * CTP + c8]);
    }
    __syncthreads();  // bsum atomics done
    if (tid < 128) {
      psum[(size_t)blk * NC + cg * 128 + tid] = bsum[tid];
      psq[(size_t)blk * NC + cg * 128 + tid] = bsq[tid];
    }
  }
}

// ---------------- column-stat reduce + BN finalize (one block per column) --------

__global__ __launch_bounds__(256) void k_finred(
    const float* __restrict__ psum, const float* __restrict__ psq, int nb, int nc,
    const float* __restrict__ g, const float* __restrict__ be,
    float* __restrict__ osc, float* __restrict__ osh, float invn) {
  __shared__ float ws[4], wq[4];
  int col = blockIdx.x;
  int t = threadIdx.x;
  float s = 0.f, q = 0.f;
  for (int b = t; b < nb; b += 256) {
    s += psum[(size_t)b * nc + col];
    q += psq[(size_t)b * nc + col];
  }
#pragma unroll
  for (int off = 32; off > 0; off >>= 1) {
    s += __shfl_xor(s, off, 64);
    q += __shfl_xor(q, off, 64);
  }
  if ((t & 63) == 0) { ws[t >> 6] = s; wq[t >> 6] = q; }
  __syncthreads();
  if (t == 0) {
    s = ws[0] + ws[1] + ws[2] + ws[3];
    q = wq[0] + wq[1] + wq[2] + wq[3];
    float m = s * invn;
    float v = fmaxf(q * invn - m * m, 0.f);
    float sc = g[col] * rsqrtf(v + BN_EPS);
    osc[col] = sc;
    osh[col] = be[col] - m * sc;
  }
}

// ---------------- BN stat finalize (classifier path) ----------------

__global__ void k_fin(const float* __restrict__ colsum, const float* __restrict__ colsq,
                      const float* __restrict__ g, const float* __restrict__ be,
                      float* __restrict__ osc, float* __restrict__ osh, int nc,
                      float invn) {
  int c = threadIdx.x;
  if (c < nc) {
    float m = colsum[c] * invn;
    float v = fmaxf(colsq[c] * invn - m * m, 0.f);
    float sc = g[c] * rsqrtf(v + BN_EPS);
    osc[c] = sc;
    osh[c] = be[c] - m * sc;
  }
}

// ---------------- pooling (batch sorted -> contiguous ranges), bf16 X ------------
// 512 threads/graph = 8 row-subgroups x 64 lanes x ushort2 (2 cols/lane).

static __device__ __forceinline__ int lb_i32(const int* a, int n, int key) {
  int lo = 0, hi = n;
  while (lo < hi) {
    int mid = (lo + hi) >> 1;
    if (a[mid] < key) lo = mid + 1; else hi = mid;
  }
  return lo;
}

__global__ __launch_bounds__(512) void k_pool(
    const unsigned short* __restrict__ X, const int* __restrict__ batch,
    const float* __restrict__ tsc, const float* __restrict__ tsh,
    float* __restrict__ z, int n) {
  __shared__ int slo, shi;
  __shared__ float ssum[8][128], smax[8][128];
  int g = blockIdx.x;
  int t = threadIdx.x;
  int sg = t >> 6;           // 0..7 row-subgroup
  int c2 = (t & 63) << 1;    // column pair base
  if (t == 0) {
    slo = lb_i32(batch, n, g);
    shi = lb_i32(batch, n, g + 1);
  }
  __syncthreads();
  int lo = slo, hi = shi;
  float a0 = tsc[c2], a1 = tsc[c2 + 1];
  float b0 = tsh[c2], b1 = tsh[c2 + 1];
  float s0 = 0.f, s1 = 0.f;
  float m0 = -3.402823466e38f, m1 = -3.402823466e38f;
  for (int i = lo + sg; i < hi; i += 8) {
    unsigned u = *(const unsigned*)(X + (size_t)i * DD + c2);
    float v0 = fmaxf(0.f, bf2f((unsigned short)(u & 0xffff)) * a0 + b0);
    float v1 = fmaxf(0.f, bf2f((unsigned short)(u >> 16)) * a1 + b1);
    s0 += v0; m0 = fmaxf(m0, v0);
    s1 += v1; m1 = fmaxf(m1, v1);
  }
  ssum[sg][c2] = s0; ssum[sg][c2 + 1] = s1;
  smax[sg][c2] = m0; smax[sg][c2 + 1] = m1;
  __syncthreads();
  if (t < 128) {
    float S = 0.f, M = -3.402823466e38f;
#pragma unroll
    for (int k = 0; k < 8; ++k) {
      S += ssum[k][t];
      M = fmaxf(M, smax[k][t]);
    }
    float cntf = (float)(hi - lo);
    z[(size_t)g * 384 + t] = S;
    z[(size_t)g * 384 + 128 + t] = S / fmaxf(cntf, 1.f);
    z[(size_t)g * 384 + 256 + t] = M;
  }
}

// ---------------- classifier head (fp32, tiny) ----------------

__global__ void k_cls1(const float* __restrict__ z, const float* __restrict__ cW1,
                       const float* __restrict__ cb1, float* __restrict__ z1,
                       float* __restrict__ colsum, float* __restrict__ colsq) {
  __shared__ float zr[384];
  int g = blockIdx.x;
  int c = threadIdx.x;  // 128
  for (int i = c; i < 384; i += 128) zr[i] = z[(size_t)g * 384 + i];
  __syncthreads();
  float s = cb1[c];
#pragma unroll 4
  for (int k = 0; k < 384; ++k) s = fmaf(zr[k], cW1[(size_t)k * 128 + c], s);
  z1[(size_t)g * 128 + c] = s;
  atomicAdd(&colsum[c], s);
  atomicAdd(&colsq[c], s * s);
}

__global__ void k_cls2(const float* __restrict__ z1, const float* __restrict__ csc,
                       const float* __restrict__ csh, const float* __restrict__ cW2,
                       const float* __restrict__ cb2, const float* __restrict__ cW3,
                       const float* __restrict__ cb3, float* __restrict__ out) {
  __shared__ float z1n[128];
  __shared__ float z2s[64];
  int g = blockIdx.x;
  int t = threadIdx.x;  // 128
  z1n[t] = fmaxf(0.f, z1[(size_t)g * 128 + t] * csc[t] + csh[t]);
  __syncthreads();
  if (t < 64) {
    float s = cb2[t];
#pragma unroll 4
    for (int k = 0; k < 128; ++k) s = fmaf(z1n[k], cW2[(size_t)k * 64 + t], s);
    z2s[t] = fmaxf(0.f, s);
  }
  __syncthreads();
  if (t < 2) {
    float s = cb3[t];
#pragma unroll 4
    for (int c = 0; c < 64; ++c) s = fmaf(z2s[c], cW3[(size_t)c * 2 + t], s);
    out[(size_t)g * 2 + t] = s;
  }
}

// ---------------- launch ----------------

extern "C" void kernel_launch(void* const* d_in, const int* in_sizes, int n_in,
                              void* d_out, int out_size, void* d_ws, size_t ws_size,
                              hipStream_t stream) {
  const float* x = (const float*)d_in[0];
  const int* ei = (const int*)d_in[1];     // int32 (harness downcasts int64)
  const int* batch = (const int*)d_in[2];  // int32
  const float* W1 = (const float*)d_in[4];
  const float* b1 = (const float*)d_in[5];
  const float* g1 = (const float*)d_in[6];
  const float* be1 = (const float*)d_in[7];
  const float* W2 = (const float*)d_in[8];
  const float* b2 = (const float*)d_in[9];
  const float* gbn = (const float*)d_in[10];
  const float* bbn = (const float*)d_in[11];
  const float* epsv = (const float*)d_in[12];
  const float* cW1 = (const float*)d_in[13];
  const float* cb1 = (const float*)d_in[14];
  const float* cg = (const float*)d_in[15];
  const float* cbeta = (const float*)d_in[16];
  const float* cW2 = (const float*)d_in[17];
  const float* cb2 = (const float*)d_in[18];
  const float* cW3 = (const float*)d_in[19];
  const float* cb3 = (const float*)d_in[20];
  float* out = (float*)d_out;

  char* p = (char*)d_ws;
  auto alloc = [&](size_t bytes) {
    char* r = p;
    p += (bytes + 255) & ~(size_t)255;
    return r;
  };
  const int NB = (NN + 127) / 128;  // 782 GEMM row-blocks
  int* cnt = (int*)alloc((size_t)NN * 4);
  int* rs = (int*)alloc((size_t)(NN + 1) * 4);
  int* cur = (int*)alloc((size_t)NN * 4);
  int* ci = (int*)alloc((size_t)EE * 4);
  int* part = (int*)alloc(128 * 4);
  int* partx = (int*)alloc(128 * 4);
  unsigned short* xbf = (unsigned short*)alloc((size_t)NN * DD * 2);
  unsigned short* h0 = (unsigned short*)alloc((size_t)NN * DD * 2);
  unsigned short* h1 = (unsigned short*)alloc((size_t)NN * 2 * DD * 2);
  unsigned short* xp = (unsigned short*)alloc((size_t)NN * DD * 2);
  float* psum = (float*)alloc((size_t)NB * 256 * 4);
  float* psq = (float*)alloc((size_t)NB * 256 * 4);
  float* stats = (float*)alloc(512 * 4);  // cls colsum[256] + colsq[256]
  float* colsum = stats;
  float* colsq = stats + 256;
  float* tsc1 = (float*)alloc(256 * 4);
  float* tsh1 = (float*)alloc(256 * 4);
  float* tscX = (float*)alloc(128 * 4);
  float* tshX = (float*)alloc(128 * 4);
  float* zbuf = (float*)alloc((size_t)GG * 384 * 4);
  float* z1 = (float*)alloc((size_t)GG * 128 * 4);
  unsigned short* W1t = (unsigned short*)alloc((size_t)4 * 256 * 128 * 2);
  unsigned short* W2t = (unsigned short*)alloc((size_t)4 * 128 * 256 * 2);
  (void)ws_size; (void)n_in; (void)in_sizes; (void)out_size;

  // weight convert+transpose to bf16 (static across layers/calls)
  k_conv<<<512, 256, 0, stream>>>(W1, W2, W1t, W2t);
  // x -> bf16
  k_x2bf<<<(NN * DD / 4 + 255) / 256, 256, 0, stream>>>(x, xbf);

  // CSR build (edges static across layers)
  hipMemsetAsync(cnt, 0, (size_t)NN * 4, stream);
  k_hist<<<(EE + 255) / 256, 256, 0, stream>>>(ei, cnt);
  const int nscan = (NN + 1023) / 1024;  // 98
  k_part<<<nscan, 1024, 0, stream>>>(cnt, part);
  k_scanpart<<<1, 128, 0, stream>>>(part, partx, nscan);
  k_rs<<<nscan, 1024, 0, stream>>>(cnt, partx, rs, cur);
  k_fill<<<(EE + 255) / 256, 256, 0, stream>>>(ei, cur, ci);

  for (int l = 0; l < LL; ++l) {
    const unsigned short* Xl = (l == 0) ? xbf : xp;
    k_agg_bf16<<<(NN * 16 + 255) / 256, 256, 0, stream>>>(
        Xl, rs, ci, epsv, l, (l > 0) ? 1 : 0, tscX, tshX, h0, NN);
    k_gemm<128, 256><<<NB, 512, 0, stream>>>(
        h0, 0, nullptr, nullptr, W1t + (size_t)l * 256 * 128,
        b1 + (size_t)l * 256, h1, psum, psq, NN);
    k_finred<<<256, 256, 0, stream>>>(psum, psq, NB, 256, g1 + (size_t)l * 256,
                                      be1 + (size_t)l * 256, tsc1, tsh1, 1.0f / NN);
    k_gemm<256, 128><<<NB, 512, 0, stream>>>(
        h1, 1, tsc1, tsh1, W2t + (size_t)l * 128 * 256,
        b2 + (size_t)l * 128, xp, psum, psq, NN);
    k_finred<<<128, 256, 0, stream>>>(psum, psq, NB, 128, gbn + (size_t)l * 128,
                                      bbn + (size_t)l * 128, tscX, tshX, 1.0f / NN);
  }

  k_pool<<<GG, 512, 0, stream>>>(xp, batch, tscX, tshX, zbuf, NN);
  hipMemsetAsync(stats, 0, 512 * 4, stream);
  k_cls1<<<GG, 128, 0, stream>>>(zbuf, cW1, cb1, z1, colsum, colsq);
  k_fin<<<1, 256, 0, stream>>>(colsum, colsq, cg, cbeta, tscX, tshX, 128, 1.0f / GG);
  k_cls2<<<GG, 128, 0, stream>>>(z1, tscX, tshX, cW2, cb2, cW3, cb3, out);
}

// Round 10
// 789.225 us; speedup vs baseline: 2.4114x; 1.0259x over previous
//
#include <hip/hip_runtime.h>
#include <cstdint>
#include <cstddef>

// Problem constants (fixed by the reference setup_inputs).
#define NN 100000
#define EE 500000
#define DD 128
#define GG 512
#define LL 4
#define BN_EPS 1e-5f

typedef __attribute__((ext_vector_type(8))) short short8;
typedef __attribute__((ext_vector_type(8))) unsigned short ushort8v;
typedef __attribute__((ext_vector_type(4))) float f32x4;

static __device__ __forceinline__ unsigned short f2bf(float f) {
  union { float f; unsigned u; } v;
  v.f = f;
  unsigned r = v.u + 0x7fffu + ((v.u >> 16) & 1u);  // RNE
  return (unsigned short)(r >> 16);
}
static __device__ __forceinline__ float bf2f(unsigned short u) {
  union { unsigned u; float f; } v;
  v.u = ((unsigned)u) << 16;
  return v.f;
}

// ---------------- CSR build (int32 inputs) ----------------

__global__ void k_hist(const int* __restrict__ ei, int* __restrict__ cnt) {
  int e = blockIdx.x * 256 + threadIdx.x;
  if (e < EE) {
    int d = ei[EE + e];
    if (d >= 0 && d < NN) atomicAdd(&cnt[d], 1);
  }
}

__global__ void k_part(const int* __restrict__ cnt, int* __restrict__ part) {
  __shared__ int sm[1024];
  int t = threadIdx.x;
  int i = blockIdx.x * 1024 + t;
  sm[t] = (i < NN) ? cnt[i] : 0;
  __syncthreads();
  for (int off = 512; off > 0; off >>= 1) {
    if (t < off) sm[t] += sm[t + off];
    __syncthreads();
  }
  if (t == 0) part[blockIdx.x] = sm[0];
}

__global__ void k_scanpart(const int* __restrict__ part, int* __restrict__ partx, int nb) {
  __shared__ int sm[128];
  int t = threadIdx.x;
  int v = (t < nb) ? part[t] : 0;
  sm[t] = v;
  __syncthreads();
  for (int off = 1; off < 128; off <<= 1) {
    int u = (t >= off) ? sm[t - off] : 0;
    __syncthreads();
    sm[t] += u;
    __syncthreads();
  }
  if (t < nb) partx[t] = sm[t] - v;
}

__global__ void k_rs(const int* __restrict__ cnt, const int* __restrict__ partx,
                     int* __restrict__ rs, int* __restrict__ cur) {
  __shared__ int sm[1024];
  int t = threadIdx.x;
  int i = blockIdx.x * 1024 + t;
  int v = (i < NN) ? cnt[i] : 0;
  sm[t] = v;
  __syncthreads();
  for (int off = 1; off < 1024; off <<= 1) {
    int u = (t >= off) ? sm[t - off] : 0;
    __syncthreads();
    sm[t] += u;
    __syncthreads();
  }
  if (i < NN) {
    int excl = partx[blockIdx.x] + sm[t] - v;
    rs[i] = excl;
    cur[i] = excl;
    if (i == NN - 1) rs[NN] = excl + v;
  }
}

__global__ void k_fill(const int* __restrict__ ei, int* __restrict__ cur,
                       int* __restrict__ ci) {
  int e = blockIdx.x * 256 + threadIdx.x;
  if (e < EE) {
    int s = ei[e];
    int d = ei[EE + e];
    if (d >= 0 && d < NN && s >= 0 && s < NN) {
      int pos = atomicAdd(&cur[d], 1);
      if (pos >= 0 && pos < EE) ci[pos] = s;  // order irrelevant (sum)
    }
  }
}

// ---------------- weight convert: W -> W^T in bf16, once per call ----------------

__global__ void k_conv(const float* __restrict__ W1, const float* __restrict__ W2,
                       unsigned short* __restrict__ W1t, unsigned short* __restrict__ W2t) {
  int idx = blockIdx.x * 256 + threadIdx.x;
  if (idx < 4 * 256 * 128) {
    {  // W1: [l][k][nc] (K=128,NC=256) -> [l][nc][k]
      int l = idx >> 15, rem = idx & 32767;
      int nc = rem >> 7, k = rem & 127;
      W1t[idx] = f2bf(W1[(l << 15) + k * 256 + nc]);
    }
    {  // W2: [l][k][nc] (K=256,NC=128) -> [l][nc][k]
      int l = idx >> 15, rem = idx & 32767;
      int nc = rem >> 8, k = rem & 255;
      W2t[idx] = f2bf(W2[(l << 15) + k * 128 + nc]);
    }
  }
}

// ---------------- x -> bf16 convert (streaming, once per call) ----------------

__global__ void k_x2bf(const float* __restrict__ x, unsigned short* __restrict__ xb) {
  int i = blockIdx.x * 256 + threadIdx.x;
  if (i < NN * DD / 4) {
    float4 v = *(const float4*)(x + (size_t)i * 4);
    ushort4 o;
    o.x = f2bf(v.x); o.y = f2bf(v.y); o.z = f2bf(v.z); o.w = f2bf(v.w);
    *(ushort4*)(xb + (size_t)i * 4) = o;
  }
}

// ---------------- aggregation: bf16 X in (opt. BN/ReLU), bf16 h0 out ----
// 16 lanes/node, ushort8 (16B) loads, 1-deep neighbor prefetch.

__global__ __launch_bounds__(256) void k_agg_bf16(
    const unsigned short* __restrict__ X, const int* __restrict__ rs,
    const int* __restrict__ ci, const float* __restrict__ epsv, int l, int mode,
    const float* __restrict__ tsc, const float* __restrict__ tsh,
    unsigned short* __restrict__ h0, int n) {
  int idx = blockIdx.x * 256 + threadIdx.x;
  int node = idx >> 4;
  int c8 = (idx & 15) << 3;
  if (node >= n) return;
  float sa[8], sb[8];
  if (mode) {
    float4 a0 = *(const float4*)(tsc + c8), a1 = *(const float4*)(tsc + c8 + 4);
    float4 b0 = *(const float4*)(tsh + c8), b1 = *(const float4*)(tsh + c8 + 4);
    sa[0] = a0.x; sa[1] = a0.y; sa[2] = a0.z; sa[3] = a0.w;
    sa[4] = a1.x; sa[5] = a1.y; sa[6] = a1.z; sa[7] = a1.w;
    sb[0] = b0.x; sb[1] = b0.y; sb[2] = b0.z; sb[3] = b0.w;
    sb[4] = b1.x; sb[5] = b1.y; sb[6] = b1.z; sb[7] = b1.w;
  }
  float se = 1.f + epsv[l];
  ushort8v v = *(const ushort8v*)(X + (size_t)node * DD + c8);
  float acc[8];
#pragma unroll
  for (int j = 0; j < 8; ++j) {
    float f = bf2f(v[j]);
    if (mode) f = fmaxf(0.f, f * sa[j] + sb[j]);
    acc[j] = se * f;
  }
  int e0 = rs[node], e1 = rs[node + 1];
  ushort8v un;
  if (e0 < e1) un = *(const ushort8v*)(X + (size_t)ci[e0] * DD + c8);
  for (int e = e0; e < e1; ++e) {
    ushort8v uc = un;
    if (e + 1 < e1) un = *(const ushort8v*)(X + (size_t)ci[e + 1] * DD + c8);
#pragma unroll
    for (int j = 0; j < 8; ++j) {
      float f = bf2f(uc[j]);
      if (mode) f = fmaxf(0.f, f * sa[j] + sb[j]);
      acc[j] += f;
    }
  }
  ushort8v o;
#pragma unroll
  for (int j = 0; j < 8; ++j) o[j] = f2bf(acc[j]);
  *(ushort8v*)(h0 + (size_t)node * DD + c8) = o;
}

// ---------------- MFMA bf16 GEMM: bf16 A (opt. BN/ReLU on read), bf16 C out ------
// GM=64 rows/block, 256 threads = 4 waves x 16 rows. BK=64 chunks, col-groups of
// 128 (8 frags/wave). Per-block column partials to psum/psq (no global atomics),
// reduced by k_finred. C staged through LDS for coalesced ushort8 stores.
// LDS ~28KB -> ~5 blocks/CU.

template <int K, int NC>
__global__ __launch_bounds__(256) void k_gemm(
    const unsigned short* __restrict__ A, int mode, const float* __restrict__ tsc,
    const float* __restrict__ tsh, const unsigned short* __restrict__ Bt,
    const float* __restrict__ bias, unsigned short* __restrict__ C,
    float* __restrict__ psum, float* __restrict__ psq, int n) {
  constexpr int KC = 64;        // k-chunk
  constexpr int KT = K / KC;    // chunks (2 or 4)
  constexpr int NT = NC / 128;  // col-groups (2 or 1)
  constexpr int AST = 72;       // stage row stride (ushorts), 144B
  constexpr int CTP = 136;      // C-tile row stride (ushorts), 272B
  __shared__ __align__(16) unsigned short smem[(64 + 128) * AST];  // 27648 B
  __shared__ float bsum[128], bsq[128];
  unsigned short* Asm = smem;             // [64][AST]
  unsigned short* Bsm = smem + 64 * AST;  // [128][AST]
  unsigned short* Ct = smem;              // epilogue reuse: [64][CTP] = 17408 B

  int tid = threadIdx.x;
  int lane = tid & 63, wave = tid >> 6;
  int quad = lane >> 4, l15 = lane & 15;
  int row0 = blockIdx.x * 64;
  int blk = blockIdx.x;

  for (int cg = 0; cg < NT; ++cg) {
    f32x4 acc[8];
#pragma unroll
    for (int j = 0; j < 8; ++j) acc[j] = (f32x4){0.f, 0.f, 0.f, 0.f};

    for (int kc = 0; kc < KT; ++kc) {
      __syncthreads();  // smem free (prior mfma / prior epilogue Ct reads done)
      // stage A chunk: 64 rows x 64 k (512 ushort8, 2/thread)
#pragma unroll
      for (int it = 0; it < 2; ++it) {
        int f = tid + it * 256;
        int r = f >> 3;
        int c8 = (f & 7) << 3;
        int gr = row0 + r;
        ushort8v v = (ushort8v){0, 0, 0, 0, 0, 0, 0, 0};
        if (gr < n) v = *(const ushort8v*)(A + (size_t)gr * K + kc * KC + c8);
        if (mode) {
          int kg = kc * KC + c8;
          float4 s0 = *(const float4*)(tsc + kg);
          float4 s1 = *(const float4*)(tsc + kg + 4);
          float4 t0 = *(const float4*)(tsh + kg);
          float4 t1 = *(const float4*)(tsh + kg + 4);
          float sa[8] = {s0.x, s0.y, s0.z, s0.w, s1.x, s1.y, s1.z, s1.w};
          float sb[8] = {t0.x, t0.y, t0.z, t0.w, t1.x, t1.y, t1.z, t1.w};
#pragma unroll
          for (int j = 0; j < 8; ++j)
            v[j] = f2bf(fmaxf(0.f, bf2f(v[j]) * sa[j] + sb[j]));
        }
        *(ushort8v*)(&Asm[r * AST + c8]) = v;
      }
      // stage B chunk: 128 cols x 64 k (1024 ushort8, 4/thread)
#pragma unroll
      for (int it = 0; it < 4; ++it) {
        int f = tid + it * 256;
        int r = f >> 3;
        int c8 = (f & 7) << 3;
        *(ushort8v*)(&Bsm[r * AST + c8]) =
            *(const ushort8v*)(Bt + (size_t)(cg * 128 + r) * K + kc * KC + c8);
      }
      if (kc == 0 && tid < 128) { bsum[tid] = 0.f; bsq[tid] = 0.f; }
      __syncthreads();
#pragma unroll
      for (int kk = 0; kk < KC; kk += 32) {
        int ko = kk + quad * 8;
        short8 av = *(const short8*)(&Asm[(wave * 16 + l15) * AST + ko]);
#pragma unroll
        for (int cf = 0; cf < 8; ++cf) {
          short8 bv = *(const short8*)(&Bsm[(cf * 16 + l15) * AST + ko]);
          acc[cf] = __builtin_amdgcn_mfma_f32_16x16x32_bf16(av, bv, acc[cf], 0, 0, 0);
        }
      }
    }

    // ---- epilogue ----
    __syncthreads();  // all mfma LDS reads done; smem reusable as Ct
    float s8[8], q8[8];
#pragma unroll
    for (int j = 0; j < 8; ++j) { s8[j] = 0.f; q8[j] = 0.f; }
    int lrbase = wave * 16 + quad * 4;  // local row base
#pragma unroll
    for (int cf = 0; cf < 8; ++cf) {
      int col = cg * 128 + cf * 16 + l15;
      float bv = bias[col];
#pragma unroll
      for (int reg = 0; reg < 4; ++reg) {
        int lr = lrbase + reg;
        float e = acc[cf][reg] + bv;
        Ct[lr * CTP + cf * 16 + l15] = f2bf(e);
        if (row0 + lr < n) { s8[cf] += e; q8[cf] += e * e; }
      }
    }
#pragma unroll
    for (int cf = 0; cf < 8; ++cf) {
      s8[cf] += __shfl_xor(s8[cf], 16, 64);
      s8[cf] += __shfl_xor(s8[cf], 32, 64);
      q8[cf] += __shfl_xor(q8[cf], 16, 64);
      q8[cf] += __shfl_xor(q8[cf], 32, 64);
    }
    __syncthreads();  // Ct complete; bsum zeroed (in kc==0 stage)
    if (quad == 0) {
#pragma unroll
      for (int cf = 0; cf < 8; ++cf) {
        atomicAdd(&bsum[cf * 16 + l15], s8[cf]);
        atomicAdd(&bsq[cf * 16 + l15], q8[cf]);
      }
    }
    // coalesced C store: 16B/lane (64 rows x 128 cols = 1024 ushort8, 4/thread)
#pragma unroll
    for (int it = 0; it < 4; ++it) {
      int f = tid + it * 256;
      int r = f >> 4;
      int c8 = (f & 15) << 3;
      int gr = row0 + r;
      if (gr < n)
        *(ushort8v*)(C + (size_t)gr * NC + cg * 128 + c8) =
            *(const ushort8v*)(&Ct[r * CTP + c8]);
    }
    __syncthreads();  // bsum atomics done
    if (tid < 128) {
      psum[(size_t)blk * NC + cg * 128 + tid] = bsum[tid];
      psq[(size_t)blk * NC + cg * 128 + tid] = bsq[tid];
    }
  }
}

// ---------------- column-stat reduce + BN finalize (one block per column) --------

__global__ __launch_bounds__(256) void k_finred(
    const float* __restrict__ psum, const float* __restrict__ psq, int nb, int nc,
    const float* __restrict__ g, const float* __restrict__ be,
    float* __restrict__ osc, float* __restrict__ osh, float invn) {
  __shared__ float ws[4], wq[4];
  int col = blockIdx.x;
  int t = threadIdx.x;
  float s = 0.f, q = 0.f;
  for (int b = t; b < nb; b += 256) {
    s += psum[(size_t)b * nc + col];
    q += psq[(size_t)b * nc + col];
  }
#pragma unroll
  for (int off = 32; off > 0; off >>= 1) {
    s += __shfl_xor(s, off, 64);
    q += __shfl_xor(q, off, 64);
  }
  if ((t & 63) == 0) { ws[t >> 6] = s; wq[t >> 6] = q; }
  __syncthreads();
  if (t == 0) {
    s = ws[0] + ws[1] + ws[2] + ws[3];
    q = wq[0] + wq[1] + wq[2] + wq[3];
    float m = s * invn;
    float v = fmaxf(q * invn - m * m, 0.f);
    float sc = g[col] * rsqrtf(v + BN_EPS);
    osc[col] = sc;
    osh[col] = be[col] - m * sc;
  }
}

// ---------------- classifier z1 stats (sum & sumsq from one array) ----------------
// one block per column; z1 is [GG][128].

__global__ __launch_bounds__(256) void k_statz(
    const float* __restrict__ z1, const float* __restrict__ g,
    const float* __restrict__ be, float* __restrict__ osc, float* __restrict__ osh) {
  __shared__ float ws[4], wq[4];
  int col = blockIdx.x;
  int t = threadIdx.x;
  float s = 0.f, q = 0.f;
  for (int b = t; b < GG; b += 256) {
    float v = z1[(size_t)b * 128 + col];
    s += v;
    q += v * v;
  }
#pragma unroll
  for (int off = 32; off > 0; off >>= 1) {
    s += __shfl_xor(s, off, 64);
    q += __shfl_xor(q, off, 64);
  }
  if ((t & 63) == 0) { ws[t >> 6] = s; wq[t >> 6] = q; }
  __syncthreads();
  if (t == 0) {
    s = ws[0] + ws[1] + ws[2] + ws[3];
    q = wq[0] + wq[1] + wq[2] + wq[3];
    float m = s / (float)GG;
    float v = fmaxf(q / (float)GG - m * m, 0.f);
    float sc = g[col] * rsqrtf(v + BN_EPS);
    osc[col] = sc;
    osh[col] = be[col] - m * sc;
  }
}

// ---------------- pooling (batch sorted -> contiguous ranges), bf16 X ------------
// 512 threads/graph = 8 row-subgroups x 64 lanes x ushort2 (2 cols/lane).

static __device__ __forceinline__ int lb_i32(const int* a, int n, int key) {
  int lo = 0, hi = n;
  while (lo < hi) {
    int mid = (lo + hi) >> 1;
    if (a[mid] < key) lo = mid + 1; else hi = mid;
  }
  return lo;
}

__global__ __launch_bounds__(512) void k_pool(
    const unsigned short* __restrict__ X, const int* __restrict__ batch,
    const float* __restrict__ tsc, const float* __restrict__ tsh,
    float* __restrict__ z, int n) {
  __shared__ int slo, shi;
  __shared__ float ssum[8][128], smax[8][128];
  int g = blockIdx.x;
  int t = threadIdx.x;
  int sg = t >> 6;           // 0..7 row-subgroup
  int c2 = (t & 63) << 1;    // column pair base
  if (t == 0) {
    slo = lb_i32(batch, n, g);
    shi = lb_i32(batch, n, g + 1);
  }
  __syncthreads();
  int lo = slo, hi = shi;
  float a0 = tsc[c2], a1 = tsc[c2 + 1];
  float b0 = tsh[c2], b1 = tsh[c2 + 1];
  float s0 = 0.f, s1 = 0.f;
  float m0 = -3.402823466e38f, m1 = -3.402823466e38f;
  for (int i = lo + sg; i < hi; i += 8) {
    unsigned u = *(const unsigned*)(X + (size_t)i * DD + c2);
    float v0 = fmaxf(0.f, bf2f((unsigned short)(u & 0xffff)) * a0 + b0);
    float v1 = fmaxf(0.f, bf2f((unsigned short)(u >> 16)) * a1 + b1);
    s0 += v0; m0 = fmaxf(m0, v0);
    s1 += v1; m1 = fmaxf(m1, v1);
  }
  ssum[sg][c2] = s0; ssum[sg][c2 + 1] = s1;
  smax[sg][c2] = m0; smax[sg][c2 + 1] = m1;
  __syncthreads();
  if (t < 128) {
    float S = 0.f, M = -3.402823466e38f;
#pragma unroll
    for (int k = 0; k < 8; ++k) {
      S += ssum[k][t];
      M = fmaxf(M, smax[k][t]);
    }
    float cntf = (float)(hi - lo);
    z[(size_t)g * 384 + t] = S;
    z[(size_t)g * 384 + 128 + t] = S / fmaxf(cntf, 1.f);
    z[(size_t)g * 384 + 256 + t] = M;
  }
}

// ---------------- classifier head (fp32, tiny; no atomics) ----------------

__global__ void k_cls1(const float* __restrict__ z, const float* __restrict__ cW1,
                       const float* __restrict__ cb1, float* __restrict__ z1) {
  __shared__ float zr[384];
  int g = blockIdx.x;
  int c = threadIdx.x;  // 128
  for (int i = c; i < 384; i += 128) zr[i] = z[(size_t)g * 384 + i];
  __syncthreads();
  float s = cb1[c];
#pragma unroll 4
  for (int k = 0; k < 384; ++k) s = fmaf(zr[k], cW1[(size_t)k * 128 + c], s);
  z1[(size_t)g * 128 + c] = s;
}

__global__ void k_cls2(const float* __restrict__ z1, const float* __restrict__ csc,
                       const float* __restrict__ csh, const float* __restrict__ cW2,
                       const float* __restrict__ cb2, const float* __restrict__ cW3,
                       const float* __restrict__ cb3, float* __restrict__ out) {
  __shared__ float z1n[128];
  __shared__ float z2s[64];
  int g = blockIdx.x;
  int t = threadIdx.x;  // 128
  z1n[t] = fmaxf(0.f, z1[(size_t)g * 128 + t] * csc[t] + csh[t]);
  __syncthreads();
  if (t < 64) {
    float s = cb2[t];
#pragma unroll 4
    for (int k = 0; k < 128; ++k) s = fmaf(z1n[k], cW2[(size_t)k * 64 + t], s);
    z2s[t] = fmaxf(0.f, s);
  }
  __syncthreads();
  if (t < 2) {
    float s = cb3[t];
#pragma unroll 4
    for (int c = 0; c < 64; ++c) s = fmaf(z2s[c], cW3[(size_t)c * 2 + t], s);
    out[(size_t)g * 2 + t] = s;
  }
}

// ---------------- launch ----------------

extern "C" void kernel_launch(void* const* d_in, const int* in_sizes, int n_in,
                              void* d_out, int out_size, void* d_ws, size_t ws_size,
                              hipStream_t stream) {
  const float* x = (const float*)d_in[0];
  const int* ei = (const int*)d_in[1];     // int32 (harness downcasts int64)
  const int* batch = (const int*)d_in[2];  // int32
  const float* W1 = (const float*)d_in[4];
  const float* b1 = (const float*)d_in[5];
  const float* g1 = (const float*)d_in[6];
  const float* be1 = (const float*)d_in[7];
  const float* W2 = (const float*)d_in[8];
  const float* b2 = (const float*)d_in[9];
  const float* gbn = (const float*)d_in[10];
  const float* bbn = (const float*)d_in[11];
  const float* epsv = (const float*)d_in[12];
  const float* cW1 = (const float*)d_in[13];
  const float* cb1 = (const float*)d_in[14];
  const float* cg = (const float*)d_in[15];
  const float* cbeta = (const float*)d_in[16];
  const float* cW2 = (const float*)d_in[17];
  const float* cb2 = (const float*)d_in[18];
  const float* cW3 = (const float*)d_in[19];
  const float* cb3 = (const float*)d_in[20];
  float* out = (float*)d_out;

  char* p = (char*)d_ws;
  auto alloc = [&](size_t bytes) {
    char* r = p;
    p += (bytes + 255) & ~(size_t)255;
    return r;
  };
  const int NB = (NN + 63) / 64;  // 1563 GEMM row-blocks
  int* cnt = (int*)alloc((size_t)NN * 4);
  int* rs = (int*)alloc((size_t)(NN + 1) * 4);
  int* cur = (int*)alloc((size_t)NN * 4);
  int* ci = (int*)alloc((size_t)EE * 4);
  int* part = (int*)alloc(128 * 4);
  int* partx = (int*)alloc(128 * 4);
  unsigned short* xbf = (unsigned short*)alloc((size_t)NN * DD * 2);
  unsigned short* h0 = (unsigned short*)alloc((size_t)NN * DD * 2);
  unsigned short* h1 = (unsigned short*)alloc((size_t)NN * 2 * DD * 2);
  unsigned short* xp = (unsigned short*)alloc((size_t)NN * DD * 2);
  float* psum = (float*)alloc((size_t)NB * 256 * 4);
  float* psq = (float*)alloc((size_t)NB * 256 * 4);
  float* tsc1 = (float*)alloc(256 * 4);
  float* tsh1 = (float*)alloc(256 * 4);
  float* tscX = (float*)alloc(128 * 4);
  float* tshX = (float*)alloc(128 * 4);
  float* zbuf = (float*)alloc((size_t)GG * 384 * 4);
  float* z1 = (float*)alloc((size_t)GG * 128 * 4);
  unsigned short* W1t = (unsigned short*)alloc((size_t)4 * 256 * 128 * 2);
  unsigned short* W2t = (unsigned short*)alloc((size_t)4 * 128 * 256 * 2);
  (void)ws_size; (void)n_in; (void)in_sizes; (void)out_size;

  // weight convert+transpose to bf16 (static across layers/calls)
  k_conv<<<512, 256, 0, stream>>>(W1, W2, W1t, W2t);
  // x -> bf16
  k_x2bf<<<(NN * DD / 4 + 255) / 256, 256, 0, stream>>>(x, xbf);

  // CSR build (edges static across layers)
  hipMemsetAsync(cnt, 0, (size_t)NN * 4, stream);
  k_hist<<<(EE + 255) / 256, 256, 0, stream>>>(ei, cnt);
  const int nscan = (NN + 1023) / 1024;  // 98
  k_part<<<nscan, 1024, 0, stream>>>(cnt, part);
  k_scanpart<<<1, 128, 0, stream>>>(part, partx, nscan);
  k_rs<<<nscan, 1024, 0, stream>>>(cnt, partx, rs, cur);
  k_fill<<<(EE + 255) / 256, 256, 0, stream>>>(ei, cur, ci);

  for (int l = 0; l < LL; ++l) {
    const unsigned short* Xl = (l == 0) ? xbf : xp;
    k_agg_bf16<<<(NN * 16 + 255) / 256, 256, 0, stream>>>(
        Xl, rs, ci, epsv, l, (l > 0) ? 1 : 0, tscX, tshX, h0, NN);
    k_gemm<128, 256><<<NB, 256, 0, stream>>>(
        h0, 0, nullptr, nullptr, W1t + (size_t)l * 256 * 128,
        b1 + (size_t)l * 256, h1, psum, psq, NN);
    k_finred<<<256, 256, 0, stream>>>(psum, psq, NB, 256, g1 + (size_t)l * 256,
                                      be1 + (size_t)l * 256, tsc1, tsh1, 1.0f / NN);
    k_gemm<256, 128><<<NB, 256, 0, stream>>>(
        h1, 1, tsc1, tsh1, W2t + (size_t)l * 128 * 256,
        b2 + (size_t)l * 128, xp, psum, psq, NN);
    k_finred<<<128, 256, 0, stream>>>(psum, psq, NB, 128, gbn + (size_t)l * 128,
                                      bbn + (size_t)l * 128, tscX, tshX, 1.0f / NN);
  }

  k_pool<<<GG, 512, 0, stream>>>(xp, batch, tscX, tshX, zbuf, NN);
  k_cls1<<<GG, 128, 0, stream>>>(zbuf, cW1, cb1, z1);
  k_statz<<<128, 256, 0, stream>>>(z1, cg, cbeta, tscX, tshX);
  k_cls2<<<GG, 128, 0, stream>>>(z1, tscX, tshX, cW2, cb2, cW3, cb3, out);
}

// Round 11
// 764.788 us; speedup vs baseline: 2.4884x; 1.0320x over previous
//
#include <hip/hip_runtime.h>
#include <cstdint>
#include <cstddef>

// Problem constants (fixed by the reference setup_inputs).
#define NN 100000
#define EE 500000
#define DD 128
#define GG 512
#define LL 4
#define BN_EPS 1e-5f

typedef __attribute__((ext_vector_type(8))) short short8;
typedef __attribute__((ext_vector_type(8))) unsigned short ushort8v;
typedef __attribute__((ext_vector_type(4))) float f32x4;

static __device__ __forceinline__ unsigned short f2bf(float f) {
  union { float f; unsigned u; } v;
  v.f = f;
  unsigned r = v.u + 0x7fffu + ((v.u >> 16) & 1u);  // RNE
  return (unsigned short)(r >> 16);
}
static __device__ __forceinline__ float bf2f(unsigned short u) {
  union { unsigned u; float f; } v;
  v.u = ((unsigned)u) << 16;
  return v.f;
}

// ---------------- CSR build (int32 inputs) ----------------

__global__ void k_hist(const int* __restrict__ ei, int* __restrict__ cnt) {
  int e = blockIdx.x * 256 + threadIdx.x;
  if (e < EE) {
    int d = ei[EE + e];
    if (d >= 0 && d < NN) atomicAdd(&cnt[d], 1);
  }
}

__global__ void k_part(const int* __restrict__ cnt, int* __restrict__ part) {
  __shared__ int sm[1024];
  int t = threadIdx.x;
  int i = blockIdx.x * 1024 + t;
  sm[t] = (i < NN) ? cnt[i] : 0;
  __syncthreads();
  for (int off = 512; off > 0; off >>= 1) {
    if (t < off) sm[t] += sm[t + off];
    __syncthreads();
  }
  if (t == 0) part[blockIdx.x] = sm[0];
}

__global__ void k_scanpart(const int* __restrict__ part, int* __restrict__ partx, int nb) {
  __shared__ int sm[128];
  int t = threadIdx.x;
  int v = (t < nb) ? part[t] : 0;
  sm[t] = v;
  __syncthreads();
  for (int off = 1; off < 128; off <<= 1) {
    int u = (t >= off) ? sm[t - off] : 0;
    __syncthreads();
    sm[t] += u;
    __syncthreads();
  }
  if (t < nb) partx[t] = sm[t] - v;
}

__global__ void k_rs(const int* __restrict__ cnt, const int* __restrict__ partx,
                     int* __restrict__ rs, int* __restrict__ cur) {
  __shared__ int sm[1024];
  int t = threadIdx.x;
  int i = blockIdx.x * 1024 + t;
  int v = (i < NN) ? cnt[i] : 0;
  sm[t] = v;
  __syncthreads();
  for (int off = 1; off < 1024; off <<= 1) {
    int u = (t >= off) ? sm[t - off] : 0;
    __syncthreads();
    sm[t] += u;
    __syncthreads();
  }
  if (i < NN) {
    int excl = partx[blockIdx.x] + sm[t] - v;
    rs[i] = excl;
    cur[i] = excl;
    if (i == NN - 1) rs[NN] = excl + v;
  }
}

__global__ void k_fill(const int* __restrict__ ei, int* __restrict__ cur,
                       int* __restrict__ ci) {
  int e = blockIdx.x * 256 + threadIdx.x;
  if (e < EE) {
    int s = ei[e];
    int d = ei[EE + e];
    if (d >= 0 && d < NN && s >= 0 && s < NN) {
      int pos = atomicAdd(&cur[d], 1);
      if (pos >= 0 && pos < EE) ci[pos] = s;  // order irrelevant (sum)
    }
  }
}

// ---------------- weight convert: W -> W^T in bf16, once per call ----------------

__global__ void k_conv(const float* __restrict__ W1, const float* __restrict__ W2,
                       unsigned short* __restrict__ W1t, unsigned short* __restrict__ W2t) {
  int idx = blockIdx.x * 256 + threadIdx.x;
  if (idx < 4 * 256 * 128) {
    {  // W1: [l][k][nc] (K=128,NC=256) -> [l][nc][k]
      int l = idx >> 15, rem = idx & 32767;
      int nc = rem >> 7, k = rem & 127;
      W1t[idx] = f2bf(W1[(l << 15) + k * 256 + nc]);
    }
    {  // W2: [l][k][nc] (K=256,NC=128) -> [l][nc][k]
      int l = idx >> 15, rem = idx & 32767;
      int nc = rem >> 8, k = rem & 255;
      W2t[idx] = f2bf(W2[(l << 15) + k * 128 + nc]);
    }
  }
}

// ---------------- x -> bf16 convert (streaming, once per call) ----------------

__global__ void k_x2bf(const float* __restrict__ x, unsigned short* __restrict__ xb) {
  int i = blockIdx.x * 256 + threadIdx.x;
  if (i < NN * DD / 4) {
    float4 v = *(const float4*)(x + (size_t)i * 4);
    ushort4 o;
    o.x = f2bf(v.x); o.y = f2bf(v.y); o.z = f2bf(v.z); o.w = f2bf(v.w);
    *(ushort4*)(xb + (size_t)i * 4) = o;
  }
}

// ---------------- aggregation: bf16 X in (opt. BN/ReLU), bf16 h0 out ----
// 16 lanes/node, ushort8 (16B) loads, 1-deep neighbor prefetch.

__global__ __launch_bounds__(256) void k_agg_bf16(
    const unsigned short* __restrict__ X, const int* __restrict__ rs,
    const int* __restrict__ ci, const float* __restrict__ epsv, int l, int mode,
    const float* __restrict__ tsc, const float* __restrict__ tsh,
    unsigned short* __restrict__ h0, int n) {
  int idx = blockIdx.x * 256 + threadIdx.x;
  int node = idx >> 4;
  int c8 = (idx & 15) << 3;
  if (node >= n) return;
  float sa[8], sb[8];
  if (mode) {
    float4 a0 = *(const float4*)(tsc + c8), a1 = *(const float4*)(tsc + c8 + 4);
    float4 b0 = *(const float4*)(tsh + c8), b1 = *(const float4*)(tsh + c8 + 4);
    sa[0] = a0.x; sa[1] = a0.y; sa[2] = a0.z; sa[3] = a0.w;
    sa[4] = a1.x; sa[5] = a1.y; sa[6] = a1.z; sa[7] = a1.w;
    sb[0] = b0.x; sb[1] = b0.y; sb[2] = b0.z; sb[3] = b0.w;
    sb[4] = b1.x; sb[5] = b1.y; sb[6] = b1.z; sb[7] = b1.w;
  }
  float se = 1.f + epsv[l];
  ushort8v v = *(const ushort8v*)(X + (size_t)node * DD + c8);
  float acc[8];
#pragma unroll
  for (int j = 0; j < 8; ++j) {
    float f = bf2f(v[j]);
    if (mode) f = fmaxf(0.f, f * sa[j] + sb[j]);
    acc[j] = se * f;
  }
  int e0 = rs[node], e1 = rs[node + 1];
  ushort8v un;
  if (e0 < e1) un = *(const ushort8v*)(X + (size_t)ci[e0] * DD + c8);
  for (int e = e0; e < e1; ++e) {
    ushort8v uc = un;
    if (e + 1 < e1) un = *(const ushort8v*)(X + (size_t)ci[e + 1] * DD + c8);
#pragma unroll
    for (int j = 0; j < 8; ++j) {
      float f = bf2f(uc[j]);
      if (mode) f = fmaxf(0.f, f * sa[j] + sb[j]);
      acc[j] += f;
    }
  }
  ushort8v o;
#pragma unroll
  for (int j = 0; j < 8; ++j) o[j] = f2bf(acc[j]);
  *(ushort8v*)(h0 + (size_t)node * DD + c8) = o;
}

// ---------------- MFMA bf16 GEMM with register-prefetch pipeline ----------------
// GM=128 rows/block, 512 threads = 8 waves x 16 rows. BK=64 phases over
// (col-group, k-chunk); phase p+1's A/B global loads are issued before phase p's
// MFMA so the load latency overlaps compute. Per-block column partials to
// psum/psq (no global atomics). C staged through LDS for coalesced stores.

template <int K, int NC>
__global__ __launch_bounds__(512) void k_gemm(
    const unsigned short* __restrict__ A, int mode, const float* __restrict__ tsc,
    const float* __restrict__ tsh, const unsigned short* __restrict__ Bt,
    const float* __restrict__ bias, unsigned short* __restrict__ C,
    float* __restrict__ psum, float* __restrict__ psq, int n) {
  constexpr int KC = 64;        // k-chunk
  constexpr int KT = K / KC;    // chunks (2 or 4)
  constexpr int NT = NC / 128;  // col-groups (2 or 1)
  constexpr int P = KT * NT;    // total phases (4)
  constexpr int AST = 72;       // stage row stride (ushorts), 144B
  constexpr int CTP = 136;      // C-tile row stride (ushorts), 272B
  __shared__ __align__(16) unsigned short smem[2 * 128 * AST];  // 36864 B
  __shared__ float bsum[128], bsq[128];
  unsigned short* Asm = smem;              // [128][AST]
  unsigned short* Bsm = smem + 128 * AST;  // [128][AST]
  unsigned short* Ct = smem;               // epilogue reuse: [128][CTP] = 34816 B

  int tid = threadIdx.x;
  int lane = tid & 63, wave = tid >> 6;
  int quad = lane >> 4, l15 = lane & 15;
  int row0 = blockIdx.x * 128;
  int blk = blockIdx.x;

  ushort8v pa[2], pb[2];
  // preload phase 0 (cg=0, kc=0)
#pragma unroll
  for (int it = 0; it < 2; ++it) {
    int f = tid + it * 512;
    int r = f >> 3;
    int c8 = (f & 7) << 3;
    int gr = row0 + r;
    pa[it] = (ushort8v){0, 0, 0, 0, 0, 0, 0, 0};
    if (gr < n) pa[it] = *(const ushort8v*)(A + (size_t)gr * K + c8);
    pb[it] = *(const ushort8v*)(Bt + (size_t)r * K + c8);
  }

  f32x4 acc[8];
  for (int p = 0; p < P; ++p) {
    int cg = p / KT, kc = p % KT;
    if (kc == 0) {
#pragma unroll
      for (int j = 0; j < 8; ++j) acc[j] = (f32x4){0.f, 0.f, 0.f, 0.f};
    }
    // write prefetched regs -> LDS (transform A if mode)
#pragma unroll
    for (int it = 0; it < 2; ++it) {
      int f = tid + it * 512;
      int r = f >> 3;
      int c8 = (f & 7) << 3;
      ushort8v v = pa[it];
      if (mode) {
        int kg = kc * KC + c8;
        float4 s0 = *(const float4*)(tsc + kg);
        float4 s1 = *(const float4*)(tsc + kg + 4);
        float4 t0 = *(const float4*)(tsh + kg);
        float4 t1 = *(const float4*)(tsh + kg + 4);
        float sa[8] = {s0.x, s0.y, s0.z, s0.w, s1.x, s1.y, s1.z, s1.w};
        float sb[8] = {t0.x, t0.y, t0.z, t0.w, t1.x, t1.y, t1.z, t1.w};
#pragma unroll
        for (int j = 0; j < 8; ++j)
          v[j] = f2bf(fmaxf(0.f, bf2f(v[j]) * sa[j] + sb[j]));
      }
      *(ushort8v*)(&Asm[r * AST + c8]) = v;
      *(ushort8v*)(&Bsm[r * AST + c8]) = pb[it];
    }
    __syncthreads();  // LDS tiles ready
    // issue phase p+1 loads (latency overlaps MFMA + epilogue below)
    if (p + 1 < P) {
      int cg2 = (p + 1) / KT, kc2 = (p + 1) % KT;
#pragma unroll
      for (int it = 0; it < 2; ++it) {
        int f = tid + it * 512;
        int r = f >> 3;
        int c8 = (f & 7) << 3;
        int gr = row0 + r;
        pa[it] = (ushort8v){0, 0, 0, 0, 0, 0, 0, 0};
        if (gr < n) pa[it] = *(const ushort8v*)(A + (size_t)gr * K + kc2 * KC + c8);
        pb[it] = *(const ushort8v*)(Bt + (size_t)(cg2 * 128 + r) * K + kc2 * KC + c8);
      }
    }
    // MFMA on current tiles
#pragma unroll
    for (int kk = 0; kk < KC; kk += 32) {
      int ko = kk + quad * 8;
      short8 av = *(const short8*)(&Asm[(wave * 16 + l15) * AST + ko]);
#pragma unroll
      for (int cf = 0; cf < 8; ++cf) {
        short8 bv = *(const short8*)(&Bsm[(cf * 16 + l15) * AST + ko]);
        acc[cf] = __builtin_amdgcn_mfma_f32_16x16x32_bf16(av, bv, acc[cf], 0, 0, 0);
      }
    }
    if (kc == KT - 1) {
      // ---- epilogue for this col-group ----
      __syncthreads();  // all MFMA LDS reads done; smem reusable as Ct
      if (tid < 128) { bsum[tid] = 0.f; bsq[tid] = 0.f; }
      float s8[8], q8[8];
#pragma unroll
      for (int j = 0; j < 8; ++j) { s8[j] = 0.f; q8[j] = 0.f; }
      int lrbase = wave * 16 + quad * 4;
#pragma unroll
      for (int cf = 0; cf < 8; ++cf) {
        int col = cg * 128 + cf * 16 + l15;
        float bv = bias[col];
#pragma unroll
        for (int reg = 0; reg < 4; ++reg) {
          int lr = lrbase + reg;
          float e = acc[cf][reg] + bv;
          Ct[lr * CTP + cf * 16 + l15] = f2bf(e);
          if (row0 + lr < n) { s8[cf] += e; q8[cf] += e * e; }
        }
      }
#pragma unroll
      for (int cf = 0; cf < 8; ++cf) {
        s8[cf] += __shfl_xor(s8[cf], 16, 64);
        s8[cf] += __shfl_xor(s8[cf], 32, 64);
        q8[cf] += __shfl_xor(q8[cf], 16, 64);
        q8[cf] += __shfl_xor(q8[cf], 32, 64);
      }
      __syncthreads();  // Ct complete; bsum zeroed
      if (quad == 0) {
#pragma unroll
        for (int cf = 0; cf < 8; ++cf) {
          atomicAdd(&bsum[cf * 16 + l15], s8[cf]);
          atomicAdd(&bsq[cf * 16 + l15], q8[cf]);
        }
      }
      // coalesced C store: 16B/lane (128 rows x 128 cols = 2048 ushort8)
#pragma unroll
      for (int it = 0; it < 4; ++it) {
        int f = tid + it * 512;
        int r = f >> 4;
        int c8 = (f & 15) << 3;
        int gr = row0 + r;
        if (gr < n)
          *(ushort8v*)(C + (size_t)gr * NC + cg * 128 + c8) =
              *(const ushort8v*)(&Ct[r * CTP + c8]);
      }
      __syncthreads();  // bsum atomics + Ct reads drained
      if (tid < 128) {
        psum[(size_t)blk * NC + cg * 128 + tid] = bsum[tid];
        psq[(size_t)blk * NC + cg * 128 + tid] = bsq[tid];
      }
    } else {
      __syncthreads();  // LDS reads done before next phase overwrites
    }
  }
}

// ---------------- column-stat reduce + BN finalize (one block per column) --------

__global__ __launch_bounds__(256) void k_finred(
    const float* __restrict__ psum, const float* __restrict__ psq, int nb, int nc,
    const float* __restrict__ g, const float* __restrict__ be,
    float* __restrict__ osc, float* __restrict__ osh, float invn) {
  __shared__ float ws[4], wq[4];
  int col = blockIdx.x;
  int t = threadIdx.x;
  float s = 0.f, q = 0.f;
  for (int b = t; b < nb; b += 256) {
    s += psum[(size_t)b * nc + col];
    q += psq[(size_t)b * nc + col];
  }
#pragma unroll
  for (int off = 32; off > 0; off >>= 1) {
    s += __shfl_xor(s, off, 64);
    q += __shfl_xor(q, off, 64);
  }
  if ((t & 63) == 0) { ws[t >> 6] = s; wq[t >> 6] = q; }
  __syncthreads();
  if (t == 0) {
    s = ws[0] + ws[1] + ws[2] + ws[3];
    q = wq[0] + wq[1] + wq[2] + wq[3];
    float m = s * invn;
    float v = fmaxf(q * invn - m * m, 0.f);
    float sc = g[col] * rsqrtf(v + BN_EPS);
    osc[col] = sc;
    osh[col] = be[col] - m * sc;
  }
}

// ---------------- classifier z1 stats (sum & sumsq from one array) ----------------

__global__ __launch_bounds__(256) void k_statz(
    const float* __restrict__ z1, const float* __restrict__ g,
    const float* __restrict__ be, float* __restrict__ osc, float* __restrict__ osh) {
  __shared__ float ws[4], wq[4];
  int col = blockIdx.x;
  int t = threadIdx.x;
  float s = 0.f, q = 0.f;
  for (int b = t; b < GG; b += 256) {
    float v = z1[(size_t)b * 128 + col];
    s += v;
    q += v * v;
  }
#pragma unroll
  for (int off = 32; off > 0; off >>= 1) {
    s += __shfl_xor(s, off, 64);
    q += __shfl_xor(q, off, 64);
  }
  if ((t & 63) == 0) { ws[t >> 6] = s; wq[t >> 6] = q; }
  __syncthreads();
  if (t == 0) {
    s = ws[0] + ws[1] + ws[2] + ws[3];
    q = wq[0] + wq[1] + wq[2] + wq[3];
    float m = s / (float)GG;
    float v = fmaxf(q / (float)GG - m * m, 0.f);
    float sc = g[col] * rsqrtf(v + BN_EPS);
    osc[col] = sc;
    osh[col] = be[col] - m * sc;
  }
}

// ---------------- pooling (batch sorted -> contiguous ranges), bf16 X ------------

static __device__ __forceinline__ int lb_i32(const int* a, int n, int key) {
  int lo = 0, hi = n;
  while (lo < hi) {
    int mid = (lo + hi) >> 1;
    if (a[mid] < key) lo = mid + 1; else hi = mid;
  }
  return lo;
}

__global__ __launch_bounds__(512) void k_pool(
    const unsigned short* __restrict__ X, const int* __restrict__ batch,
    const float* __restrict__ tsc, const float* __restrict__ tsh,
    float* __restrict__ z, int n) {
  __shared__ int slo, shi;
  __shared__ float ssum[8][128], smax[8][128];
  int g = blockIdx.x;
  int t = threadIdx.x;
  int sg = t >> 6;           // 0..7 row-subgroup
  int c2 = (t & 63) << 1;    // column pair base
  if (t == 0) {
    slo = lb_i32(batch, n, g);
    shi = lb_i32(batch, n, g + 1);
  }
  __syncthreads();
  int lo = slo, hi = shi;
  float a0 = tsc[c2], a1 = tsc[c2 + 1];
  float b0 = tsh[c2], b1 = tsh[c2 + 1];
  float s0 = 0.f, s1 = 0.f;
  float m0 = -3.402823466e38f, m1 = -3.402823466e38f;
  for (int i = lo + sg; i < hi; i += 8) {
    unsigned u = *(const unsigned*)(X + (size_t)i * DD + c2);
    float v0 = fmaxf(0.f, bf2f((unsigned short)(u & 0xffff)) * a0 + b0);
    float v1 = fmaxf(0.f, bf2f((unsigned short)(u >> 16)) * a1 + b1);
    s0 += v0; m0 = fmaxf(m0, v0);
    s1 += v1; m1 = fmaxf(m1, v1);
  }
  ssum[sg][c2] = s0; ssum[sg][c2 + 1] = s1;
  smax[sg][c2] = m0; smax[sg][c2 + 1] = m1;
  __syncthreads();
  if (t < 128) {
    float S = 0.f, M = -3.402823466e38f;
#pragma unroll
    for (int k = 0; k < 8; ++k) {
      S += ssum[k][t];
      M = fmaxf(M, smax[k][t]);
    }
    float cntf = (float)(hi - lo);
    z[(size_t)g * 384 + t] = S;
    z[(size_t)g * 384 + 128 + t] = S / fmaxf(cntf, 1.f);
    z[(size_t)g * 384 + 256 + t] = M;
  }
}

// ---------------- classifier head (fp32, tiny; no atomics) ----------------

__global__ void k_cls1(const float* __restrict__ z, const float* __restrict__ cW1,
                       const float* __restrict__ cb1, float* __restrict__ z1) {
  __shared__ float zr[384];
  int g = blockIdx.x;
  int c = threadIdx.x;  // 128
  for (int i = c; i < 384; i += 128) zr[i] = z[(size_t)g * 384 + i];
  __syncthreads();
  float s = cb1[c];
#pragma unroll 4
  for (int k = 0; k < 384; ++k) s = fmaf(zr[k], cW1[(size_t)k * 128 + c], s);
  z1[(size_t)g * 128 + c] = s;
}

__global__ void k_cls2(const float* __restrict__ z1, const float* __restrict__ csc,
                       const float* __restrict__ csh, const float* __restrict__ cW2,
                       const float* __restrict__ cb2, const float* __restrict__ cW3,
                       const float* __restrict__ cb3, float* __restrict__ out) {
  __shared__ float z1n[128];
  __shared__ float z2s[64];
  int g = blockIdx.x;
  int t = threadIdx.x;  // 128
  z1n[t] = fmaxf(0.f, z1[(size_t)g * 128 + t] * csc[t] + csh[t]);
  __syncthreads();
  if (t < 64) {
    float s = cb2[t];
#pragma unroll 4
    for (int k = 0; k < 128; ++k) s = fmaf(z1n[k], cW2[(size_t)k * 64 + t], s);
    z2s[t] = fmaxf(0.f, s);
  }
  __syncthreads();
  if (t < 2) {
    float s = cb3[t];
#pragma unroll 4
    for (int c = 0; c < 64; ++c) s = fmaf(z2s[c], cW3[(size_t)c * 2 + t], s);
    out[(size_t)g * 2 + t] = s;
  }
}

// ---------------- launch ----------------

extern "C" void kernel_launch(void* const* d_in, const int* in_sizes, int n_in,
                              void* d_out, int out_size, void* d_ws, size_t ws_size,
                              hipStream_t stream) {
  const float* x = (const float*)d_in[0];
  const int* ei = (const int*)d_in[1];     // int32 (harness downcasts int64)
  const int* batch = (const int*)d_in[2];  // int32
  const float* W1 = (const float*)d_in[4];
  const float* b1 = (const float*)d_in[5];
  const float* g1 = (const float*)d_in[6];
  const float* be1 = (const float*)d_in[7];
  const float* W2 = (const float*)d_in[8];
  const float* b2 = (const float*)d_in[9];
  const float* gbn = (const float*)d_in[10];
  const float* bbn = (const float*)d_in[11];
  const float* epsv = (const float*)d_in[12];
  const float* cW1 = (const float*)d_in[13];
  const float* cb1 = (const float*)d_in[14];
  const float* cg = (const float*)d_in[15];
  const float* cbeta = (const float*)d_in[16];
  const float* cW2 = (const float*)d_in[17];
  const float* cb2 = (const float*)d_in[18];
  const float* cW3 = (const float*)d_in[19];
  const float* cb3 = (const float*)d_in[20];
  float* out = (float*)d_out;

  char* p = (char*)d_ws;
  auto alloc = [&](size_t bytes) {
    char* r = p;
    p += (bytes + 255) & ~(size_t)255;
    return r;
  };
  const int NB = (NN + 127) / 128;  // 782 GEMM row-blocks
  int* cnt = (int*)alloc((size_t)NN * 4);
  int* rs = (int*)alloc((size_t)(NN + 1) * 4);
  int* cur = (int*)alloc((size_t)NN * 4);
  int* ci = (int*)alloc((size_t)EE * 4);
  int* part = (int*)alloc(128 * 4);
  int* partx = (int*)alloc(128 * 4);
  unsigned short* xbf = (unsigned short*)alloc((size_t)NN * DD * 2);
  unsigned short* h0 = (unsigned short*)alloc((size_t)NN * DD * 2);
  unsigned short* h1 = (unsigned short*)alloc((size_t)NN * 2 * DD * 2);
  unsigned short* xp = (unsigned short*)alloc((size_t)NN * DD * 2);
  float* psum = (float*)alloc((size_t)NB * 256 * 4);
  float* psq = (float*)alloc((size_t)NB * 256 * 4);
  float* tsc1 = (float*)alloc(256 * 4);
  float* tsh1 = (float*)alloc(256 * 4);
  float* tscX = (float*)alloc(128 * 4);
  float* tshX = (float*)alloc(128 * 4);
  float* zbuf = (float*)alloc((size_t)GG * 384 * 4);
  float* z1 = (float*)alloc((size_t)GG * 128 * 4);
  unsigned short* W1t = (unsigned short*)alloc((size_t)4 * 256 * 128 * 2);
  unsigned short* W2t = (unsigned short*)alloc((size_t)4 * 128 * 256 * 2);
  (void)ws_size; (void)n_in; (void)in_sizes; (void)out_size;

  // weight convert+transpose to bf16 (static across layers/calls)
  k_conv<<<512, 256, 0, stream>>>(W1, W2, W1t, W2t);
  // x -> bf16
  k_x2bf<<<(NN * DD / 4 + 255) / 256, 256, 0, stream>>>(x, xbf);

  // CSR build (edges static across layers)
  hipMemsetAsync(cnt, 0, (size_t)NN * 4, stream);
  k_hist<<<(EE + 255) / 256, 256, 0, stream>>>(ei, cnt);
  const int nscan = (NN + 1023) / 1024;  // 98
  k_part<<<nscan, 1024, 0, stream>>>(cnt, part);
  k_scanpart<<<1, 128, 0, stream>>>(part, partx, nscan);
  k_rs<<<nscan, 1024, 0, stream>>>(cnt, partx, rs, cur);
  k_fill<<<(EE + 255) / 256, 256, 0, stream>>>(ei, cur, ci);

  for (int l = 0; l < LL; ++l) {
    const unsigned short* Xl = (l == 0) ? xbf : xp;
    k_agg_bf16<<<(NN * 16 + 255) / 256, 256, 0, stream>>>(
        Xl, rs, ci, epsv, l, (l > 0) ? 1 : 0, tscX, tshX, h0, NN);
    k_gemm<128, 256><<<NB, 512, 0, stream>>>(
        h0, 0, nullptr, nullptr, W1t + (size_t)l * 256 * 128,
        b1 + (size_t)l * 256, h1, psum, psq, NN);
    k_finred<<<256, 256, 0, stream>>>(psum, psq, NB, 256, g1 + (size_t)l * 256,
                                      be1 + (size_t)l * 256, tsc1, tsh1, 1.0f / NN);
    k_gemm<256, 128><<<NB, 512, 0, stream>>>(
        h1, 1, tsc1, tsh1, W2t + (size_t)l * 128 * 256,
        b2 + (size_t)l * 128, xp, psum, psq, NN);
    k_finred<<<128, 256, 0, stream>>>(psum, psq, NB, 128, gbn + (size_t)l * 128,
                                      bbn + (size_t)l * 128, tscX, tshX, 1.0f / NN);
  }

  k_pool<<<GG, 512, 0, stream>>>(xp, batch, tscX, tshX, zbuf, NN);
  k_cls1<<<GG, 128, 0, stream>>>(zbuf, cW1, cb1, z1);
  k_statz<<<128, 256, 0, stream>>>(z1, cg, cbeta, tscX, tshX);
  k_cls2<<<GG, 128, 0, stream>>>(z1, tscX, tshX, cW2, cb2, cW3, cb3, out);
}